// Round 1
// baseline (2478.315 us; speedup 1.0000x reference)
//
#include <hip/hip_runtime.h>
#include <math.h>

#define NSEQ 32768

// ---------------------------------------------------------------------------
// K1: x_mid[b,h,n,d] = (x @ Wx + bx)[b,n,h*64+d] + rope_proj[b,n,d]
// grid: (BN/64, H) ; block 256. Tile 64(M) x 64(N=one head), K=256 in chunks of 64.
// ---------------------------------------------------------------------------
__global__ __launch_bounds__(256) void k1_gemm_rope(
    const float* __restrict__ x, const float* __restrict__ pos,
    const float* __restrict__ Wx, const float* __restrict__ bx,
    const float* __restrict__ Wr, const float* __restrict__ br,
    float* __restrict__ xmid)
{
  __shared__ float As[64][68];   // [k][m]  (68 keeps rows 16B-aligned: 272B)
  __shared__ float Bs[64][68];   // [k][n]
  __shared__ float ropes[64][65];// [m_local][d]
  const int tid = threadIdx.x;
  const int m0 = blockIdx.x * 64;
  const int h  = blockIdx.y;
  const int n0 = h * 64;
  const int tx = tid & 15, ty = tid >> 4;
  const int lm = tid >> 2;            // 0..63
  const int lk = (tid & 3) * 16;      // 0,16,32,48

  // RoPE: per token 6 trig features @ Wr[6][64] + br
  {
    const int ml = lm;
    const int dq = lk;
    const int m  = m0 + ml;
    const float LL = 3.0700661520567703f; // log(10000)/3
    float a0 = pos[m*3+0];                 // inv_freq[0] = 1
    float a1 = pos[m*3+1] * expf(-LL);
    float a2 = pos[m*3+2] * expf(-2.f*LL);
    float s0=sinf(a0), c0=cosf(a0);
    float s1=sinf(a1), c1=cosf(a1);
    float s2=sinf(a2), c2=cosf(a2);
    #pragma unroll
    for (int i=0;i<16;i++){
      int d = dq+i;
      float v = br[d];
      v = fmaf(s0, Wr[0*64+d], v);
      v = fmaf(s1, Wr[1*64+d], v);
      v = fmaf(s2, Wr[2*64+d], v);
      v = fmaf(c0, Wr[3*64+d], v);
      v = fmaf(c1, Wr[4*64+d], v);
      v = fmaf(c2, Wr[5*64+d], v);
      ropes[ml][d] = v;
    }
  }

  float acc[4][4] = {};
  for (int k0 = 0; k0 < 256; k0 += 64){
    __syncthreads();
    const float* asrc = x + (size_t)(m0+lm)*256 + k0 + lk;
    #pragma unroll
    for (int i=0;i<4;i++){
      float4 v = *(const float4*)(asrc + i*4);
      As[lk+i*4+0][lm]=v.x; As[lk+i*4+1][lm]=v.y;
      As[lk+i*4+2][lm]=v.z; As[lk+i*4+3][lm]=v.w;
    }
    const float* bsrc = Wx + (size_t)(k0+lm)*512 + n0 + lk;
    #pragma unroll
    for (int i=0;i<4;i++)
      *(float4*)&Bs[lm][lk + i*4] = *(const float4*)(bsrc + i*4);
    __syncthreads();
    #pragma unroll 8
    for (int kk=0;kk<64;kk++){
      float4 a4 = *(const float4*)&As[kk][ty*4];
      float4 b4 = *(const float4*)&Bs[kk][tx*4];
      float av[4]={a4.x,a4.y,a4.z,a4.w};
      float bv[4]={b4.x,b4.y,b4.z,b4.w};
      #pragma unroll
      for (int i=0;i<4;i++)
        #pragma unroll
        for (int j=0;j<4;j++) acc[i][j] = fmaf(av[i],bv[j],acc[i][j]);
    }
  }
  #pragma unroll
  for (int i=0;i<4;i++){
    const int m = m0 + ty*4 + i;
    const int b = m >> 15, n = m & 32767;
    float4 o;
    o.x = acc[i][0] + bx[n0+tx*4+0] + ropes[ty*4+i][tx*4+0];
    o.y = acc[i][1] + bx[n0+tx*4+1] + ropes[ty*4+i][tx*4+1];
    o.z = acc[i][2] + bx[n0+tx*4+2] + ropes[ty*4+i][tx*4+2];
    o.w = acc[i][3] + bx[n0+tx*4+3] + ropes[ty*4+i][tx*4+3];
    *(float4*)(xmid + (((size_t)(b*8+h)*NSEQ + n)*64) + tx*4) = o;
  }
}

// ---------------------------------------------------------------------------
// K2: per token (one wave each): temp MLP, slice logits, gumbel-softmax sw,
// store sw, accumulate partial st (G x D) + snorm per block chunk.
// grid: (32 chunks... actually 64 chunks of 512 tokens, 16 bh); block 256 (4 waves).
// ---------------------------------------------------------------------------
__global__ __launch_bounds__(256,1) void k2_token(
  const float* __restrict__ xmid, const float* __restrict__ gum,
  const float* __restrict__ W1, const float* __restrict__ b1,
  const float* __restrict__ W2, const float* __restrict__ b2,
  const float* __restrict__ biasp,
  const float* __restrict__ Ws, const float* __restrict__ bs,
  float* __restrict__ swout, float* __restrict__ part)
{
  const int tid = threadIdx.x;
  const int wave = tid >> 6, lane = tid & 63;
  const int bh = blockIdx.y, chunk = blockIdx.x;
  const int h = bh & 7;
  __shared__ float red[64][65];
  __shared__ float redsn[64];

  // weight columns for this lane's g
  float W1c[64], Wsc[64];
  #pragma unroll
  for (int d=0;d<64;d++){ W1c[d]=W1[d*64+lane]; Wsc[d]=Ws[d*64+lane]; }
  const float b1v = b1[lane], bsv = bs[lane], W2v = W2[lane];
  const float b2v = b2[0], biash = biasp[h];

  float st_acc[64];
  #pragma unroll
  for (int d=0;d<64;d++) st_acc[d]=0.f;
  float sn_acc = 0.f;

  const size_t rowbase = (size_t)bh * NSEQ;
  const int n_base = chunk*512 + wave*128;
  for (int t=0;t<128;t++){
    const int n = n_base + t;
    const size_t row = (rowbase + n)*64;
    float xv = xmid[row + lane];
    float t1 = b1v, lg = bsv;
    #pragma unroll
    for (int d=0;d<64;d++){
      float xd = __shfl(xv, d);
      t1 = fmaf(xd, W1c[d], t1);
      lg = fmaf(xd, Wsc[d], lg);
    }
    t1 = 0.5f*t1*(1.f+erff(t1*0.7071067811865475f)); // exact gelu
    float p = t1 * W2v;
    #pragma unroll
    for (int o=32;o>0;o>>=1) p += __shfl_xor(p,o);
    float t2 = p + b2v;
    t2 = 0.5f*t2*(1.f+erff(t2*0.7071067811865475f));
    float temp = fmaxf(t2 + biash, 0.01f);
    float u = gum[row + lane];
    float gn = -logf(-logf(u+1e-8f)+1e-8f);
    float z = (lg + gn)/temp;
    float mx = z;
    #pragma unroll
    for (int o=32;o>0;o>>=1) mx = fmaxf(mx, __shfl_xor(mx,o));
    float e = expf(z-mx);
    float se = e;
    #pragma unroll
    for (int o=32;o>0;o>>=1) se += __shfl_xor(se,o);
    float swv = e/se;
    swout[row + lane] = swv;
    sn_acc += swv;
    #pragma unroll
    for (int d=0;d<64;d++) st_acc[d] = fmaf(swv, __shfl(xv,d), st_acc[d]);
  }
  __syncthreads();
  for (int w=0;w<4;w++){
    if (wave==w){
      if (w==0){
        #pragma unroll
        for (int d=0;d<64;d++) red[lane][d] = st_acc[d];
        redsn[lane] = sn_acc;
      } else {
        #pragma unroll
        for (int d=0;d<64;d++) red[lane][d] += st_acc[d];
        redsn[lane] += sn_acc;
      }
    }
    __syncthreads();
  }
  float* pb = part + ((size_t)bh*64 + chunk)*4160;
  for (int i=tid;i<4096;i+=256) pb[i] = red[i>>6][i&63];
  if (tid<64) pb[4096+tid] = redsn[tid];
}

// ---------------------------------------------------------------------------
// K3: per (b,h): reduce partials -> st, SDPA over G=64, gate, then
// M[b,h,g,c] = sum_d out_st_gated[g][d] * Wo[h*64+d][c]
// grid: 16 blocks x 256 threads
// ---------------------------------------------------------------------------
__global__ __launch_bounds__(256) void k3_slice(
    const float* __restrict__ part,
    const float* __restrict__ Wq, const float* __restrict__ Wk, const float* __restrict__ Wv,
    const float* __restrict__ Wg1, const float* __restrict__ bg1,
    const float* __restrict__ Wg2, const float* __restrict__ bg2,
    const float* __restrict__ Wo, float* __restrict__ M)
{
  const int bh = blockIdx.x;
  const int h = bh & 7;
  const int tid = threadIdx.x;
  __shared__ float st[64][65];
  __shared__ float q[64][65];
  __shared__ float kk[64][65];
  __shared__ float v[64][65];
  __shared__ float attn[64][65];
  __shared__ float outst[64][65];
  __shared__ float h1[64][65];
  __shared__ float sn[64];

  const float* pb = part + (size_t)bh*64*4160;
  for (int i=tid;i<4160;i+=256){
    float s=0.f;
    for (int c=0;c<64;c++) s += pb[(size_t)c*4160 + i];
    if (i<4096) st[i>>6][i&63]=s; else sn[i-4096]=s;
  }
  __syncthreads();
  for (int i=tid;i<4096;i+=256){ int g=i>>6,d=i&63; st[g][d] = st[g][d]/(sn[g]+1e-5f); }
  __syncthreads();
  for (int i=tid;i<4096;i+=256){
    int g=i>>6,d=i&63;
    float aq=0,ak=0,av=0;
    for (int c=0;c<64;c++){
      float s=st[g][c];
      aq = fmaf(s, Wq[c*64+d], aq);
      ak = fmaf(s, Wk[c*64+d], ak);
      av = fmaf(s, Wv[c*64+d], av);
    }
    q[g][d]=aq; kk[g][d]=ak; v[g][d]=av;
  }
  __syncthreads();
  for (int i=tid;i<4096;i+=256){
    int g=i>>6,j=i&63; float s=0.f;
    for (int c=0;c<64;c++) s = fmaf(q[g][c], kk[j][c], s);
    attn[g][j]=s*0.125f;
  }
  __syncthreads();
  if (tid<64){
    float mx=-1e30f;
    for(int j=0;j<64;j++) mx=fmaxf(mx,attn[tid][j]);
    float s=0.f;
    for(int j=0;j<64;j++){ float e=expf(attn[tid][j]-mx); attn[tid][j]=e; s+=e; }
    float inv=1.f/s;
    for(int j=0;j<64;j++) attn[tid][j]*=inv;
  }
  __syncthreads();
  for (int i=tid;i<4096;i+=256){
    int g=i>>6,d=i&63; float s=0.f;
    for (int c=0;c<64;c++) s = fmaf(attn[g][c], v[c][d], s);
    outst[g][d]=s;
  }
  __syncthreads();
  for (int i=tid;i<4096;i+=256){
    int g=i>>6,d=i&63; float s=bg1[d];
    for (int c=0;c<64;c++){
      s = fmaf(st[g][c],    Wg1[c*64+d], s);
      s = fmaf(outst[g][c], Wg1[(64+c)*64+d], s);
    }
    h1[g][d] = s/(1.f+expf(-s));  // silu
  }
  __syncthreads();
  for (int i=tid;i<4096;i+=256){
    int g=i>>6,d=i&63; float s=bg2[d];
    for (int c=0;c<64;c++) s = fmaf(h1[g][c], Wg2[c*64+d], s);
    float gate = 1.f/(1.f+expf(-s));
    q[g][d] = gate*outst[g][d];   // reuse q as gated out_st
  }
  __syncthreads();
  for (int i=tid;i<16384;i+=256){
    int g=i>>8, c=i&255; float s=0.f;
    for (int d=0;d<64;d++) s = fmaf(q[g][d], Wo[(size_t)(h*64+d)*256 + c], s);
    M[(size_t)bh*16384 + g*256 + c]=s;
  }
}

// ---------------------------------------------------------------------------
// K4: out[b,n,c] = sum_{h,g} sw[b,h,n,g] * M[b,h,g,c] + bo[c]
// grid: (BN/64, 2); tile 64(M) x 128(C), K = 512 in 8 chunks (one per h).
// ---------------------------------------------------------------------------
__global__ __launch_bounds__(256) void k4_out(
  const float* __restrict__ swb, const float* __restrict__ Mm,
  const float* __restrict__ bo, float* __restrict__ out)
{
  __shared__ float As[64][68];    // [g][tok]
  __shared__ float Bs[64][132];   // [g][c] (132*4B = 528B row, 16B aligned)
  const int tid = threadIdx.x;
  const int m0 = blockIdx.x * 64;
  const int c0 = blockIdx.y * 128;
  const int tx = tid & 15, ty = tid >> 4;
  const int lm = tid >> 2, lk = (tid & 3)*16;   // A-load indices
  const int brow = tid >> 2, bq = (tid & 3)*32; // B-load indices
  const int b = m0 >> 15;
  const int nn = m0 & 32767;
  float acc[4][8] = {};
  for (int hh=0; hh<8; hh++){
    __syncthreads();
    const int bh = b*8+hh;
    const float* asrc = swb + ((size_t)bh*NSEQ + nn + lm)*64 + lk;
    #pragma unroll
    for (int i=0;i<4;i++){
      float4 vv = *(const float4*)(asrc + i*4);
      As[lk+i*4+0][lm]=vv.x; As[lk+i*4+1][lm]=vv.y;
      As[lk+i*4+2][lm]=vv.z; As[lk+i*4+3][lm]=vv.w;
    }
    const float* bsrc = Mm + ((size_t)bh*64 + brow)*256 + c0 + bq;
    #pragma unroll
    for (int i=0;i<8;i++)
      *(float4*)&Bs[brow][bq + i*4] = *(const float4*)(bsrc + i*4);
    __syncthreads();
    #pragma unroll 4
    for (int g=0; g<64; g++){
      float4 a4 = *(const float4*)&As[g][ty*4];
      float4 b4a = *(const float4*)&Bs[g][tx*8];
      float4 b4b = *(const float4*)&Bs[g][tx*8+4];
      float av[4]={a4.x,a4.y,a4.z,a4.w};
      float bv[8]={b4a.x,b4a.y,b4a.z,b4a.w,b4b.x,b4b.y,b4b.z,b4b.w};
      #pragma unroll
      for (int i=0;i<4;i++)
        #pragma unroll
        for (int j=0;j<8;j++) acc[i][j] = fmaf(av[i],bv[j],acc[i][j]);
    }
  }
  #pragma unroll
  for (int i=0;i<4;i++){
    const int m = m0 + ty*4 + i;
    float4 o0, o1;
    o0.x = acc[i][0] + bo[c0+tx*8+0];
    o0.y = acc[i][1] + bo[c0+tx*8+1];
    o0.z = acc[i][2] + bo[c0+tx*8+2];
    o0.w = acc[i][3] + bo[c0+tx*8+3];
    o1.x = acc[i][4] + bo[c0+tx*8+4];
    o1.y = acc[i][5] + bo[c0+tx*8+5];
    o1.z = acc[i][6] + bo[c0+tx*8+6];
    o1.w = acc[i][7] + bo[c0+tx*8+7];
    *(float4*)(out + (size_t)m*256 + c0 + tx*8)     = o0;
    *(float4*)(out + (size_t)m*256 + c0 + tx*8 + 4) = o1;
  }
}

// ---------------------------------------------------------------------------
extern "C" void kernel_launch(void* const* d_in, const int* in_sizes, int n_in,
                              void* d_out, int out_size, void* d_ws, size_t ws_size,
                              hipStream_t stream) {
  (void)in_sizes; (void)n_in; (void)out_size;
  const float* x    = (const float*)d_in[0];
  const float* pos  = (const float*)d_in[1];
  const float* gum  = (const float*)d_in[2];
  const float* Wx   = (const float*)d_in[3];
  const float* bx   = (const float*)d_in[4];
  const float* W1   = (const float*)d_in[5];
  const float* b1   = (const float*)d_in[6];
  const float* W2   = (const float*)d_in[7];
  const float* b2   = (const float*)d_in[8];
  const float* bias = (const float*)d_in[9];
  const float* Wr   = (const float*)d_in[10];
  const float* br   = (const float*)d_in[11];
  const float* Ws   = (const float*)d_in[12];
  const float* bs   = (const float*)d_in[13];
  const float* Wq   = (const float*)d_in[14];
  const float* Wk   = (const float*)d_in[15];
  const float* Wv   = (const float*)d_in[16];
  const float* Wg1  = (const float*)d_in[17];
  const float* bg1  = (const float*)d_in[18];
  const float* Wg2  = (const float*)d_in[19];
  const float* bg2  = (const float*)d_in[20];
  const float* Wo   = (const float*)d_in[21];
  const float* bo   = (const float*)d_in[22];
  float* out = (float*)d_out;

  // workspace layout (floats)
  float* xmid  = (float*)d_ws;                       // 33,554,432
  float* swb   = xmid + (size_t)33554432;            // 33,554,432
  float* partp = swb  + (size_t)33554432;            // 16*64*4160 = 4,259,840
  float* Mm    = partp + (size_t)16*64*4160;         // 262,144
  const size_t need = ((size_t)33554432*2 + 4259840 + 262144) * 4;
  if (ws_size < need) return;  // workspace too small; fail loudly (output untouched)

  k1_gemm_rope<<<dim3(1024,8), 256, 0, stream>>>(x, pos, Wx, bx, Wr, br, xmid);
  k2_token<<<dim3(64,16), 256, 0, stream>>>(xmid, gum, W1, b1, W2, b2, bias, Ws, bs, swb, partp);
  k3_slice<<<16, 256, 0, stream>>>(partp, Wq, Wk, Wv, Wg1, bg1, Wg2, bg2, Wo, Mm);
  k4_out<<<dim3(1024,2), 256, 0, stream>>>(swb, Mm, bo, out);
}

// Round 2
// 954.133 us; speedup vs baseline: 2.5975x; 2.5975x over previous
//
#include <hip/hip_runtime.h>
#include <math.h>

#define NSEQ 32768

// ---------------------------------------------------------------------------
// K1: x_mid[b,h,n,d] = (x @ Wx + bx)[b,n,h*64+d] + rope_proj[b,n,d]
// grid: (BN/64, H) ; block 256. Tile 64(M) x 64(N=one head), K=256 in chunks of 64.
// ---------------------------------------------------------------------------
__global__ __launch_bounds__(256) void k1_gemm_rope(
    const float* __restrict__ x, const float* __restrict__ pos,
    const float* __restrict__ Wx, const float* __restrict__ bx,
    const float* __restrict__ Wr, const float* __restrict__ br,
    float* __restrict__ xmid)
{
  __shared__ float As[64][68];   // [k][m]
  __shared__ float Bs[64][68];   // [k][n]
  __shared__ float ropes[64][65];// [m_local][d]
  const int tid = threadIdx.x;
  const int m0 = blockIdx.x * 64;
  const int h  = blockIdx.y;
  const int n0 = h * 64;
  const int tx = tid & 15, ty = tid >> 4;
  const int lm = tid >> 2;            // 0..63
  const int lk = (tid & 3) * 16;      // 0,16,32,48

  {
    const int ml = lm;
    const int dq = lk;
    const int m  = m0 + ml;
    const float LL = 3.0700661520567703f; // log(10000)/3
    float a0 = pos[m*3+0];
    float a1 = pos[m*3+1] * expf(-LL);
    float a2 = pos[m*3+2] * expf(-2.f*LL);
    float s0=sinf(a0), c0=cosf(a0);
    float s1=sinf(a1), c1=cosf(a1);
    float s2=sinf(a2), c2=cosf(a2);
    #pragma unroll
    for (int i=0;i<16;i++){
      int d = dq+i;
      float v = br[d];
      v = fmaf(s0, Wr[0*64+d], v);
      v = fmaf(s1, Wr[1*64+d], v);
      v = fmaf(s2, Wr[2*64+d], v);
      v = fmaf(c0, Wr[3*64+d], v);
      v = fmaf(c1, Wr[4*64+d], v);
      v = fmaf(c2, Wr[5*64+d], v);
      ropes[ml][d] = v;
    }
  }

  float acc[4][4] = {};
  for (int k0 = 0; k0 < 256; k0 += 64){
    __syncthreads();
    const float* asrc = x + (size_t)(m0+lm)*256 + k0 + lk;
    #pragma unroll
    for (int i=0;i<4;i++){
      float4 v = *(const float4*)(asrc + i*4);
      As[lk+i*4+0][lm]=v.x; As[lk+i*4+1][lm]=v.y;
      As[lk+i*4+2][lm]=v.z; As[lk+i*4+3][lm]=v.w;
    }
    const float* bsrc = Wx + (size_t)(k0+lm)*512 + n0 + lk;
    #pragma unroll
    for (int i=0;i<4;i++)
      *(float4*)&Bs[lm][lk + i*4] = *(const float4*)(bsrc + i*4);
    __syncthreads();
    #pragma unroll 8
    for (int kk=0;kk<64;kk++){
      float4 a4 = *(const float4*)&As[kk][ty*4];
      float4 b4 = *(const float4*)&Bs[kk][tx*4];
      float av[4]={a4.x,a4.y,a4.z,a4.w};
      float bv[4]={b4.x,b4.y,b4.z,b4.w};
      #pragma unroll
      for (int i=0;i<4;i++)
        #pragma unroll
        for (int j=0;j<4;j++) acc[i][j] = fmaf(av[i],bv[j],acc[i][j]);
    }
  }
  #pragma unroll
  for (int i=0;i<4;i++){
    const int m = m0 + ty*4 + i;
    const int b = m >> 15, n = m & 32767;
    float4 o;
    o.x = acc[i][0] + bx[n0+tx*4+0] + ropes[ty*4+i][tx*4+0];
    o.y = acc[i][1] + bx[n0+tx*4+1] + ropes[ty*4+i][tx*4+1];
    o.z = acc[i][2] + bx[n0+tx*4+2] + ropes[ty*4+i][tx*4+2];
    o.w = acc[i][3] + bx[n0+tx*4+3] + ropes[ty*4+i][tx*4+3];
    *(float4*)(xmid + (((size_t)(b*8+h)*NSEQ + n)*64) + tx*4) = o;
  }
}

// ---------------------------------------------------------------------------
// K2 (rewritten): tiled. One block = one (bh, 512-token chunk).
// Per 64-token sub-tile:
//   GEMM1: t1 = x@W1, lg = x@Ws  (C[m][g]: m-group=ty, g-group=tx, 4x4/thread)
//   row-reduce t2 = gelu(t1)@W2 via 16-lane shfl_xor (rows within one wave)
//   gumbel-softmax in registers (gum staged via sws LDS tile)
//   st-GEMM: st[g][d] += sw^T @ x (C[g][d]: g-group=ty, d-group=tx)
// ---------------------------------------------------------------------------
__global__ __launch_bounds__(256,1) void k2_tile(
  const float* __restrict__ xmid, const float* __restrict__ gum,
  const float* __restrict__ W1, const float* __restrict__ b1,
  const float* __restrict__ W2, const float* __restrict__ b2,
  const float* __restrict__ biasp,
  const float* __restrict__ Ws, const float* __restrict__ bs,
  float* __restrict__ swout, float* __restrict__ part)
{
  __shared__ float Xm[64][68];    // x tile, token-major [m][d]
  __shared__ float sws[64][68];   // gum staging, then sw tile [m][g]
  __shared__ float W1s[64][64];   // [d][g]
  __shared__ float Wss[64][64];   // [d][g]

  const int tid = threadIdx.x;
  const int tx = tid & 15, ty = tid >> 4;
  const int bh = blockIdx.y, chunk = blockIdx.x;
  const int h = bh & 7;
  const size_t rowbase = (size_t)bh * NSEQ;

  // stage weights (once per block)
  {
    const int r = tid >> 2, cq = (tid & 3) * 16;
    #pragma unroll
    for (int i=0;i<4;i++){
      *(float4*)&W1s[r][cq + i*4] = *(const float4*)(W1 + r*64 + cq + i*4);
      *(float4*)&Wss[r][cq + i*4] = *(const float4*)(Ws + r*64 + cq + i*4);
    }
  }
  // per-thread small params
  float4 b1v = *(const float4*)(b1 + tx*4);
  float4 bsv = *(const float4*)(bs + tx*4);
  float4 W2v = *(const float4*)(W2 + tx*4);
  const float b2v = b2[0], biash = biasp[h];

  float acc2[4][4] = {};   // st partial: g=ty*4+i, d=tx*4+j
  float sn_acc[4] = {};    // snorm partial per g (valid in all tx, written by tx==0)

  const int lm = tid >> 2, lk = (tid & 3) * 16;

  for (int sub = 0; sub < 8; ++sub){
    const int n0 = chunk*512 + sub*64;
    __syncthreads();   // protect Xm/sws from previous iteration's readers
    // stage x tile and gum tile
    {
      const float* xsrc = xmid + (rowbase + n0 + lm)*64 + lk;
      const float* gsrc = gum  + (rowbase + n0 + lm)*64 + lk;
      #pragma unroll
      for (int i=0;i<4;i++){
        *(float4*)&Xm[lm][lk + i*4]  = *(const float4*)(xsrc + i*4);
        *(float4*)&sws[lm][lk + i*4] = *(const float4*)(gsrc + i*4);
      }
    }
    __syncthreads();

    // GEMM1: t1[m][g], lg[m][g]; m = ty*4+i, g = tx*4+j
    float t1a[4][4] = {};
    float lga[4][4] = {};
    for (int kk=0;kk<64;kk+=4){
      float4 a[4];
      #pragma unroll
      for (int i=0;i<4;i++) a[i] = *(const float4*)&Xm[ty*4+i][kk];
      #pragma unroll
      for (int t=0;t<4;t++){
        float4 w1r = *(const float4*)&W1s[kk+t][tx*4];
        float4 wsr = *(const float4*)&Wss[kk+t][tx*4];
        float bw1[4]={w1r.x,w1r.y,w1r.z,w1r.w};
        float bws[4]={wsr.x,wsr.y,wsr.z,wsr.w};
        #pragma unroll
        for (int i=0;i<4;i++){
          float av = ((const float*)&a[i])[t];
          #pragma unroll
          for (int j=0;j<4;j++){
            t1a[i][j] = fmaf(av, bw1[j], t1a[i][j]);
            lga[i][j] = fmaf(av, bws[j], lga[i][j]);
          }
        }
      }
    }

    // temperature: t2[m] = gelu( gelu(t1)@W2 + b2 ), temp = max(t2+bias, .01)
    float temp[4];
    {
      float bb1[4]={b1v.x,b1v.y,b1v.z,b1v.w};
      float ww2[4]={W2v.x,W2v.y,W2v.z,W2v.w};
      #pragma unroll
      for (int i=0;i<4;i++){
        float p = 0.f;
        #pragma unroll
        for (int j=0;j<4;j++){
          float t = t1a[i][j] + bb1[j];
          t = 0.5f*t*(1.f+erff(t*0.7071067811865475f));
          p = fmaf(t, ww2[j], p);
        }
        #pragma unroll
        for (int o=8;o>0;o>>=1) p += __shfl_xor(p, o);
        float t2 = p + b2v;
        t2 = 0.5f*t2*(1.f+erff(t2*0.7071067811865475f));
        temp[i] = fmaxf(t2 + biash, 0.01f);
      }
    }

    // gumbel-softmax: z = (lg + gnoise)/temp, softmax over g (row)
    float swr[4][4];
    {
      float bbs[4]={bsv.x,bsv.y,bsv.z,bsv.w};
      #pragma unroll
      for (int i=0;i<4;i++){
        float z[4];
        #pragma unroll
        for (int j=0;j<4;j++){
          float u = sws[ty*4+i][tx*4+j];
          float gn = -logf(-logf(u+1e-8f)+1e-8f);
          z[j] = (lga[i][j] + bbs[j] + gn) / temp[i];
        }
        float mx = fmaxf(fmaxf(z[0],z[1]),fmaxf(z[2],z[3]));
        #pragma unroll
        for (int o=8;o>0;o>>=1) mx = fmaxf(mx, __shfl_xor(mx, o));
        float se = 0.f;
        #pragma unroll
        for (int j=0;j<4;j++){ z[j] = expf(z[j]-mx); se += z[j]; }
        #pragma unroll
        for (int o=8;o>0;o>>=1) se += __shfl_xor(se, o);
        float inv = 1.f/se;
        #pragma unroll
        for (int j=0;j<4;j++) swr[i][j] = z[j]*inv;
      }
    }

    // store sw: own 4x4 into LDS (safe: each thread r/w only its own cells)
    // and write to global
    #pragma unroll
    for (int i=0;i<4;i++){
      float4 o = make_float4(swr[i][0],swr[i][1],swr[i][2],swr[i][3]);
      *(float4*)&sws[ty*4+i][tx*4] = o;
      *(float4*)(swout + (rowbase + n0 + ty*4+i)*64 + tx*4) = o;
    }
    __syncthreads();

    // st-GEMM: acc2[g][d] += sum_m sw[m][g] * x[m][d]; g=ty*4+i, d=tx*4+j
    for (int kk=0;kk<64;kk++){
      float4 b = *(const float4*)&Xm[kk][tx*4];
      float bv[4]={b.x,b.y,b.z,b.w};
      #pragma unroll
      for (int i=0;i<4;i++){
        float av = sws[kk][ty*4+i];
        sn_acc[i] += av;
        #pragma unroll
        for (int j=0;j<4;j++) acc2[i][j] = fmaf(av, bv[j], acc2[i][j]);
      }
    }
  }

  // write partials: [bh][chunk][4160] = st(64x64) + sn(64)
  float* pb = part + ((size_t)bh*64 + chunk)*4160;
  #pragma unroll
  for (int i=0;i<4;i++)
    *(float4*)&pb[(ty*4+i)*64 + tx*4] =
      make_float4(acc2[i][0],acc2[i][1],acc2[i][2],acc2[i][3]);
  if (tx==0){
    #pragma unroll
    for (int i=0;i<4;i++) pb[4096 + ty*4+i] = sn_acc[i] * 0.0625f * 16.f; // = sn_acc[i]
  }
}

// ---------------------------------------------------------------------------
// K3: per (b,h): reduce partials -> st, SDPA over G=64, gate, then
// M[b,h,g,c] = sum_d out_st_gated[g][d] * Wo[h*64+d][c]
// ---------------------------------------------------------------------------
__global__ __launch_bounds__(256) void k3_slice(
    const float* __restrict__ part,
    const float* __restrict__ Wq, const float* __restrict__ Wk, const float* __restrict__ Wv,
    const float* __restrict__ Wg1, const float* __restrict__ bg1,
    const float* __restrict__ Wg2, const float* __restrict__ bg2,
    const float* __restrict__ Wo, float* __restrict__ M)
{
  const int bh = blockIdx.x;
  const int h = bh & 7;
  const int tid = threadIdx.x;
  __shared__ float st[64][65];
  __shared__ float q[64][65];
  __shared__ float kk[64][65];
  __shared__ float v[64][65];
  __shared__ float attn[64][65];
  __shared__ float outst[64][65];
  __shared__ float h1[64][65];
  __shared__ float sn[64];

  const float* pb = part + (size_t)bh*64*4160;
  for (int i=tid;i<4160;i+=256){
    float s=0.f;
    for (int c=0;c<64;c++) s += pb[(size_t)c*4160 + i];
    if (i<4096) st[i>>6][i&63]=s; else sn[i-4096]=s;
  }
  __syncthreads();
  for (int i=tid;i<4096;i+=256){ int g=i>>6,d=i&63; st[g][d] = st[g][d]/(sn[g]+1e-5f); }
  __syncthreads();
  for (int i=tid;i<4096;i+=256){
    int g=i>>6,d=i&63;
    float aq=0,ak=0,av=0;
    for (int c=0;c<64;c++){
      float s=st[g][c];
      aq = fmaf(s, Wq[c*64+d], aq);
      ak = fmaf(s, Wk[c*64+d], ak);
      av = fmaf(s, Wv[c*64+d], av);
    }
    q[g][d]=aq; kk[g][d]=ak; v[g][d]=av;
  }
  __syncthreads();
  for (int i=tid;i<4096;i+=256){
    int g=i>>6,j=i&63; float s=0.f;
    for (int c=0;c<64;c++) s = fmaf(q[g][c], kk[j][c], s);
    attn[g][j]=s*0.125f;
  }
  __syncthreads();
  if (tid<64){
    float mx=-1e30f;
    for(int j=0;j<64;j++) mx=fmaxf(mx,attn[tid][j]);
    float s=0.f;
    for(int j=0;j<64;j++){ float e=expf(attn[tid][j]-mx); attn[tid][j]=e; s+=e; }
    float inv=1.f/s;
    for(int j=0;j<64;j++) attn[tid][j]*=inv;
  }
  __syncthreads();
  for (int i=tid;i<4096;i+=256){
    int g=i>>6,d=i&63; float s=0.f;
    for (int c=0;c<64;c++) s = fmaf(attn[g][c], v[c][d], s);
    outst[g][d]=s;
  }
  __syncthreads();
  for (int i=tid;i<4096;i+=256){
    int g=i>>6,d=i&63; float s=bg1[d];
    for (int c=0;c<64;c++){
      s = fmaf(st[g][c],    Wg1[c*64+d], s);
      s = fmaf(outst[g][c], Wg1[(64+c)*64+d], s);
    }
    h1[g][d] = s/(1.f+expf(-s));  // silu
  }
  __syncthreads();
  for (int i=tid;i<4096;i+=256){
    int g=i>>6,d=i&63; float s=bg2[d];
    for (int c=0;c<64;c++) s = fmaf(h1[g][c], Wg2[c*64+d], s);
    float gate = 1.f/(1.f+expf(-s));
    q[g][d] = gate*outst[g][d];   // reuse q as gated out_st
  }
  __syncthreads();
  for (int i=tid;i<16384;i+=256){
    int g=i>>8, c=i&255; float s=0.f;
    for (int d=0;d<64;d++) s = fmaf(q[g][d], Wo[(size_t)(h*64+d)*256 + c], s);
    M[(size_t)bh*16384 + g*256 + c]=s;
  }
}

// ---------------------------------------------------------------------------
// K4: out[b,n,c] = sum_{h,g} sw[b,h,n,g] * M[b,h,g,c] + bo[c]
// ---------------------------------------------------------------------------
__global__ __launch_bounds__(256) void k4_out(
  const float* __restrict__ swb, const float* __restrict__ Mm,
  const float* __restrict__ bo, float* __restrict__ out)
{
  __shared__ float As[64][68];    // [g][tok]
  __shared__ float Bs[64][132];   // [g][c]
  const int tid = threadIdx.x;
  const int m0 = blockIdx.x * 64;
  const int c0 = blockIdx.y * 128;
  const int tx = tid & 15, ty = tid >> 4;
  const int lm = tid >> 2, lk = (tid & 3)*16;
  const int brow = tid >> 2, bq = (tid & 3)*32;
  const int b = m0 >> 15;
  const int nn = m0 & 32767;
  float acc[4][8] = {};
  for (int hh=0; hh<8; hh++){
    __syncthreads();
    const int bh = b*8+hh;
    const float* asrc = swb + ((size_t)bh*NSEQ + nn + lm)*64 + lk;
    #pragma unroll
    for (int i=0;i<4;i++){
      float4 vv = *(const float4*)(asrc + i*4);
      As[lk+i*4+0][lm]=vv.x; As[lk+i*4+1][lm]=vv.y;
      As[lk+i*4+2][lm]=vv.z; As[lk+i*4+3][lm]=vv.w;
    }
    const float* bsrc = Mm + ((size_t)bh*64 + brow)*256 + c0 + bq;
    #pragma unroll
    for (int i=0;i<8;i++)
      *(float4*)&Bs[brow][bq + i*4] = *(const float4*)(bsrc + i*4);
    __syncthreads();
    #pragma unroll 4
    for (int g=0; g<64; g++){
      float4 a4 = *(const float4*)&As[g][ty*4];
      float4 b4a = *(const float4*)&Bs[g][tx*8];
      float4 b4b = *(const float4*)&Bs[g][tx*8+4];
      float av[4]={a4.x,a4.y,a4.z,a4.w};
      float bv[8]={b4a.x,b4a.y,b4a.z,b4a.w,b4b.x,b4b.y,b4b.z,b4b.w};
      #pragma unroll
      for (int i=0;i<4;i++)
        #pragma unroll
        for (int j=0;j<8;j++) acc[i][j] = fmaf(av[i],bv[j],acc[i][j]);
    }
  }
  #pragma unroll
  for (int i=0;i<4;i++){
    const int m = m0 + ty*4 + i;
    float4 o0, o1;
    o0.x = acc[i][0] + bo[c0+tx*8+0];
    o0.y = acc[i][1] + bo[c0+tx*8+1];
    o0.z = acc[i][2] + bo[c0+tx*8+2];
    o0.w = acc[i][3] + bo[c0+tx*8+3];
    o1.x = acc[i][4] + bo[c0+tx*8+4];
    o1.y = acc[i][5] + bo[c0+tx*8+5];
    o1.z = acc[i][6] + bo[c0+tx*8+6];
    o1.w = acc[i][7] + bo[c0+tx*8+7];
    *(float4*)(out + (size_t)m*256 + c0 + tx*8)     = o0;
    *(float4*)(out + (size_t)m*256 + c0 + tx*8 + 4) = o1;
  }
}

// ---------------------------------------------------------------------------
extern "C" void kernel_launch(void* const* d_in, const int* in_sizes, int n_in,
                              void* d_out, int out_size, void* d_ws, size_t ws_size,
                              hipStream_t stream) {
  (void)in_sizes; (void)n_in; (void)out_size;
  const float* x    = (const float*)d_in[0];
  const float* pos  = (const float*)d_in[1];
  const float* gum  = (const float*)d_in[2];
  const float* Wx   = (const float*)d_in[3];
  const float* bx   = (const float*)d_in[4];
  const float* W1   = (const float*)d_in[5];
  const float* b1   = (const float*)d_in[6];
  const float* W2   = (const float*)d_in[7];
  const float* b2   = (const float*)d_in[8];
  const float* bias = (const float*)d_in[9];
  const float* Wr   = (const float*)d_in[10];
  const float* br   = (const float*)d_in[11];
  const float* Ws   = (const float*)d_in[12];
  const float* bs   = (const float*)d_in[13];
  const float* Wq   = (const float*)d_in[14];
  const float* Wk   = (const float*)d_in[15];
  const float* Wv   = (const float*)d_in[16];
  const float* Wg1  = (const float*)d_in[17];
  const float* bg1  = (const float*)d_in[18];
  const float* Wg2  = (const float*)d_in[19];
  const float* bg2  = (const float*)d_in[20];
  const float* Wo   = (const float*)d_in[21];
  const float* bo   = (const float*)d_in[22];
  float* out = (float*)d_out;

  float* xmid  = (float*)d_ws;                       // 33,554,432
  float* swb   = xmid + (size_t)33554432;            // 33,554,432
  float* partp = swb  + (size_t)33554432;            // 16*64*4160
  float* Mm    = partp + (size_t)16*64*4160;         // 262,144
  const size_t need = ((size_t)33554432*2 + 4259840 + 262144) * 4;
  if (ws_size < need) return;

  k1_gemm_rope<<<dim3(1024,8), 256, 0, stream>>>(x, pos, Wx, bx, Wr, br, xmid);
  k2_tile<<<dim3(64,16), 256, 0, stream>>>(xmid, gum, W1, b1, W2, b2, bias, Ws, bs, swb, partp);
  k3_slice<<<16, 256, 0, stream>>>(partp, Wq, Wk, Wv, Wg1, bg1, Wg2, bg2, Wo, Mm);
  k4_out<<<dim3(1024,2), 256, 0, stream>>>(swb, Mm, bo, out);
}

// Round 3
// 681.436 us; speedup vs baseline: 3.6369x; 1.4002x over previous
//
#include <hip/hip_runtime.h>
#include <math.h>

#define NSEQ 32768

using short8v = __attribute__((ext_vector_type(8))) short;
using f32x4   = __attribute__((ext_vector_type(4))) float;
#define MFMA16 __builtin_amdgcn_mfma_f32_16x16x32_bf16

__device__ __forceinline__ unsigned short f2bf(float f){
  union{float f; unsigned u;} v; v.f = f;
  return (unsigned short)((v.u + 0x7FFFu + ((v.u>>16)&1u))>>16);
}
__device__ __forceinline__ float bf2f(unsigned short h){
  union{unsigned u; float f;} v; v.u = ((unsigned)h)<<16; return v.f;
}
__device__ __forceinline__ void split2(float f, unsigned short* h, unsigned short* l){
  unsigned short hh = f2bf(f);
  *h = hh; *l = f2bf(f - bf2f(hh));
}
__device__ __forceinline__ float gelu_f(float x){
  return 0.5f*x*(1.f + erff(x*0.70710678118654752f));
}

// ---------------------------------------------------------------------------
// K1: xmid[b,h,n,d] = (x @ Wx + bx)[b,n,h*64+d] + rope (fp32 out, split-bf16 MFMA)
// grid (1024, 8), block 256 (4 waves). Tile 64(m) x 64(n), K=256 in 2 chunks of 128.
// ---------------------------------------------------------------------------
__global__ __launch_bounds__(256,2) void k1_gemm_rope(
    const float* __restrict__ x, const float* __restrict__ pos,
    const float* __restrict__ Wx, const float* __restrict__ bx,
    const float* __restrict__ Wr, const float* __restrict__ br,
    float* __restrict__ xmid)
{
  __shared__ unsigned short Ah[64*136], Al[64*136];  // [m][k] pad 136
  __shared__ unsigned short Bh[64*136], Bl[64*136];  // [n][k]
  const int tid = threadIdx.x;
  const int wave = tid>>6, lane = tid&63, l15 = lane&15, lq = lane>>4;
  const int m0 = blockIdx.x*64, h = blockIdx.y, n0g = h*64;

  f32x4 acc[4] = {};

  for (int c0 = 0; c0 < 256; c0 += 128){
    __syncthreads();
    { // A stage: x tile 64x128
      const int lm = tid>>2, lkq = (tid&3)*32;
      const float* src = x + (size_t)(m0+lm)*256 + c0 + lkq;
      #pragma unroll
      for (int i=0;i<8;i++){
        float4 v = *(const float4*)(src + i*4);
        ushort4 hh, ll;
        split2(v.x,&hh.x,&ll.x); split2(v.y,&hh.y,&ll.y);
        split2(v.z,&hh.z,&ll.z); split2(v.w,&hh.w,&ll.w);
        *(ushort4*)&Ah[lm*136 + lkq + i*4] = hh;
        *(ushort4*)&Al[lm*136 + lkq + i*4] = ll;
      }
      // B stage: Wx[k][n] -> [n][k] transpose
      const int lk = tid>>1, lnq = (tid&1)*32;
      const float* bsrc = Wx + (size_t)(c0+lk)*512 + n0g + lnq;
      #pragma unroll
      for (int i=0;i<8;i++){
        float4 v = *(const float4*)(bsrc + i*4);
        float vv[4] = {v.x,v.y,v.z,v.w};
        #pragma unroll
        for (int j=0;j<4;j++){
          unsigned short hh, ll; split2(vv[j], &hh, &ll);
          Bh[(lnq+i*4+j)*136 + lk] = hh;
          Bl[(lnq+i*4+j)*136 + lk] = ll;
        }
      }
    }
    __syncthreads();
    #pragma unroll
    for (int ks=0; ks<4; ks++){
      const int koff = ks*32 + lq*8;
      short8v aH = *(const short8v*)&Ah[(wave*16 + l15)*136 + koff];
      short8v aL = *(const short8v*)&Al[(wave*16 + l15)*136 + koff];
      #pragma unroll
      for (int j=0;j<4;j++){
        short8v bH = *(const short8v*)&Bh[(j*16 + l15)*136 + koff];
        short8v bL = *(const short8v*)&Bl[(j*16 + l15)*136 + koff];
        acc[j] = MFMA16(aH,bH,acc[j],0,0,0);
        acc[j] = MFMA16(aH,bL,acc[j],0,0,0);
        acc[j] = MFMA16(aL,bH,acc[j],0,0,0);
      }
    }
  }
  __syncthreads();
  float* ropes = (float*)Ah; // 64*65 f32 = 16640 B <= 17408 B
  {
    const int ml = tid>>2, dq = (tid&3)*16;
    const int m  = m0 + ml;
    float a0 = pos[m*3+0];
    float a1 = pos[m*3+1] * 0.046415888336127774f;  // 10000^(-1/3)
    float a2 = pos[m*3+2] * 0.002154434690031884f;  // 10000^(-2/3)
    float s0=sinf(a0), c0v=cosf(a0);
    float s1=sinf(a1), c1=cosf(a1);
    float s2=sinf(a2), c2=cosf(a2);
    #pragma unroll
    for (int i=0;i<16;i++){
      int d = dq+i;
      float v = br[d];
      v = fmaf(s0, Wr[0*64+d], v);
      v = fmaf(s1, Wr[1*64+d], v);
      v = fmaf(s2, Wr[2*64+d], v);
      v = fmaf(c0v, Wr[3*64+d], v);
      v = fmaf(c1, Wr[4*64+d], v);
      v = fmaf(c2, Wr[5*64+d], v);
      ropes[ml*65+d] = v;
    }
  }
  __syncthreads();
  #pragma unroll
  for (int j=0;j<4;j++){
    #pragma unroll
    for (int r=0;r<4;r++){
      int mloc = wave*16 + lq*4 + r;
      int col = j*16 + l15;
      int m = m0 + mloc, b = m>>15, n = m & 32767;
      xmid[(((size_t)(b*8+h))*NSEQ + n)*64 + col] =
        acc[j][r] + bx[n0g+col] + ropes[mloc*65+col];
    }
  }
}

// ---------------------------------------------------------------------------
// K2: per (bh, 512-token chunk), 512 threads (8 waves), subtiles of 128 tokens.
// GEMM1' D1[g][m] = W^T x^T via MFMA (split); temp+gumbel-softmax fp32;
// st-GEMM D2[g][d] = sw^T x via MFMA (split). sw out as packed bf16 hi/lo pairs.
// ---------------------------------------------------------------------------
__global__ __launch_bounds__(512,1) void k2_tile(
  const float* __restrict__ xmid, const float* __restrict__ gum,
  const float* __restrict__ W1, const float* __restrict__ b1,
  const float* __restrict__ W2, const float* __restrict__ b2,
  const float* __restrict__ biasp,
  const float* __restrict__ Ws, const float* __restrict__ bs,
  unsigned* __restrict__ swT, float* __restrict__ part)
{
  __shared__ unsigned short XAh[128*72], XAl[128*72];   // [m][d]
  __shared__ unsigned short XBh[64*136], XBl[64*136];   // [d][m]
  __shared__ unsigned short W1h[64*72], W1l[64*72];     // [g][d]
  __shared__ unsigned short Wsh[64*72], Wsl[64*72];
  __shared__ unsigned short swh[64*136], swl[64*136];   // [g][m]
  __shared__ float snred[8*64];
  __shared__ float prm[200];

  const int tid = threadIdx.x;
  const int wave = tid>>6, lane = tid&63, l15 = lane&15, lq = lane>>4;
  const int bh = blockIdx.y, chunk = blockIdx.x, h = bh&7;
  const size_t rowbase = (size_t)bh*NSEQ;

  { // stage weights transposed + params
    const int ld = tid>>3, lg8 = (tid&7)*8;
    #pragma unroll
    for (int i=0;i<2;i++){
      float4 v1 = *(const float4*)(W1 + ld*64 + lg8 + i*4);
      float4 vs = *(const float4*)(Ws + ld*64 + lg8 + i*4);
      float a1[4]={v1.x,v1.y,v1.z,v1.w}, as[4]={vs.x,vs.y,vs.z,vs.w};
      #pragma unroll
      for (int j=0;j<4;j++){
        unsigned short hh,ll;
        split2(a1[j],&hh,&ll);
        W1h[(lg8+i*4+j)*72+ld]=hh; W1l[(lg8+i*4+j)*72+ld]=ll;
        split2(as[j],&hh,&ll);
        Wsh[(lg8+i*4+j)*72+ld]=hh; Wsl[(lg8+i*4+j)*72+ld]=ll;
      }
    }
    if (tid<64){ prm[tid]=b1[tid]; prm[64+tid]=bs[tid]; prm[128+tid]=W2[tid]; }
    if (tid==64){ prm[192]=b2[0]; prm[193]=biasp[h]; }
  }

  f32x4 acc2[2] = {};
  float snacc[4][4] = {};
  const int gt2 = wave>>1, dbase = (wave&1)*2;

  for (int sub=0; sub<4; ++sub){
    const int n0 = chunk*512 + sub*128;
    __syncthreads();
    { // stage XA [m][d] and XB [d][m] (split)
      const int lm = tid>>2, ldq = (tid&3)*16;
      const float* src = xmid + (rowbase + n0 + lm)*64 + ldq;
      #pragma unroll
      for (int i=0;i<4;i++){
        float4 v = *(const float4*)(src + i*4);
        float vv[4]={v.x,v.y,v.z,v.w};
        ushort4 hh, ll;
        unsigned short* hp=(unsigned short*)&hh; unsigned short* lp=(unsigned short*)&ll;
        #pragma unroll
        for (int j=0;j<4;j++) split2(vv[j], &hp[j], &lp[j]);
        *(ushort4*)&XAh[lm*72 + ldq + i*4] = hh;
        *(ushort4*)&XAl[lm*72 + ldq + i*4] = ll;
        #pragma unroll
        for (int j=0;j<4;j++){
          XBh[(ldq+i*4+j)*136 + lm] = hp[j];
          XBl[(ldq+i*4+j)*136 + lm] = lp[j];
        }
      }
    }
    __syncthreads();

    // prefetch gumbel row for this lane's token (hide HBM latency under MFMA)
    const int mloc = wave*16 + l15;
    const float* grow = gum + (rowbase + n0 + mloc)*64;
    float gu[4][4];
    #pragma unroll
    for (int gt=0; gt<4; gt++)
      #pragma unroll
      for (int r=0;r<4;r++) gu[gt][r] = grow[gt*16 + lq*4 + r];

    // GEMM1': D1[g][m], A=W^T [g][d], B=X [m][d]
    f32x4 t1a[4] = {}, lga[4] = {};
    #pragma unroll
    for (int ks=0; ks<2; ks++){
      const int koff = ks*32 + lq*8;
      short8v xH = *(const short8v*)&XAh[(wave*16+l15)*72 + koff];
      short8v xL = *(const short8v*)&XAl[(wave*16+l15)*72 + koff];
      #pragma unroll
      for (int gt=0; gt<4; gt++){
        const int aoff = (gt*16+l15)*72 + koff;
        short8v wH = *(const short8v*)&W1h[aoff];
        short8v wL = *(const short8v*)&W1l[aoff];
        t1a[gt] = MFMA16(wH,xH,t1a[gt],0,0,0);
        t1a[gt] = MFMA16(wH,xL,t1a[gt],0,0,0);
        t1a[gt] = MFMA16(wL,xH,t1a[gt],0,0,0);
        short8v sH = *(const short8v*)&Wsh[aoff];
        short8v sL = *(const short8v*)&Wsl[aoff];
        lga[gt] = MFMA16(sH,xH,lga[gt],0,0,0);
        lga[gt] = MFMA16(sH,xL,lga[gt],0,0,0);
        lga[gt] = MFMA16(sL,xH,lga[gt],0,0,0);
      }
    }

    // temperature (per token = per lane)
    float p = 0.f;
    #pragma unroll
    for (int gt=0; gt<4; gt++)
      #pragma unroll
      for (int r=0;r<4;r++){
        int g = gt*16 + lq*4 + r;
        p += gelu_f(t1a[gt][r] + prm[g]) * prm[128+g];
      }
    p += __shfl_xor(p,16); p += __shfl_xor(p,32);
    float t2 = gelu_f(p + prm[192]);
    float rtemp = 1.f / fmaxf(t2 + prm[193], 0.01f);

    // gumbel softmax over g
    float z[4][4]; float mx = -1e30f;
    #pragma unroll
    for (int gt=0; gt<4; gt++)
      #pragma unroll
      for (int r=0;r<4;r++){
        int g = gt*16 + lq*4 + r;
        float gn = -__logf(-__logf(gu[gt][r]+1e-8f)+1e-8f);
        float zz = (lga[gt][r] + prm[64+g] + gn)*rtemp;
        z[gt][r]=zz; mx = fmaxf(mx, zz);
      }
    mx = fmaxf(mx, __shfl_xor(mx,16)); mx = fmaxf(mx, __shfl_xor(mx,32));
    float se = 0.f;
    #pragma unroll
    for (int gt=0; gt<4; gt++)
      #pragma unroll
      for (int r=0;r<4;r++){ float e = __expf(z[gt][r]-mx); z[gt][r]=e; se += e; }
    se += __shfl_xor(se,16); se += __shfl_xor(se,32);
    float inv = 1.f/se;
    #pragma unroll
    for (int gt=0; gt<4; gt++)
      #pragma unroll
      for (int r=0;r<4;r++){
        float swv = z[gt][r]*inv;
        snacc[gt][r] += swv;
        int g = gt*16 + lq*4 + r;
        unsigned short hh,ll; split2(swv,&hh,&ll);
        swh[g*136 + mloc] = hh; swl[g*136 + mloc] = ll;
      }
    __syncthreads();

    { // write sw to global as packed (hi | lo<<16), layout [bh][g][n]
      const int g = tid>>3, mq = (tid&7)*16;
      #pragma unroll
      for (int i=0;i<4;i++){
        ushort4 hh = *(const ushort4*)&swh[g*136 + mq + i*4];
        ushort4 ll = *(const ushort4*)&swl[g*136 + mq + i*4];
        uint4 pk;
        pk.x = (unsigned)hh.x | ((unsigned)ll.x<<16);
        pk.y = (unsigned)hh.y | ((unsigned)ll.y<<16);
        pk.z = (unsigned)hh.z | ((unsigned)ll.z<<16);
        pk.w = (unsigned)hh.w | ((unsigned)ll.w<<16);
        *(uint4*)(swT + ((size_t)bh*64 + g)*NSEQ + n0 + mq + i*4) = pk;
      }
    }

    // st-GEMM: D2[g][d] += sw^T X, A=sw [g][m], B=X [d][m]
    #pragma unroll
    for (int ks=0; ks<4; ks++){
      const int koff = ks*32 + lq*8;
      short8v aH = *(const short8v*)&swh[(gt2*16+l15)*136 + koff];
      short8v aL = *(const short8v*)&swl[(gt2*16+l15)*136 + koff];
      #pragma unroll
      for (int dt=0; dt<2; dt++){
        const int boff = ((dbase+dt)*16+l15)*136 + koff;
        short8v bH = *(const short8v*)&XBh[boff];
        short8v bL = *(const short8v*)&XBl[boff];
        acc2[dt] = MFMA16(aH,bH,acc2[dt],0,0,0);
        acc2[dt] = MFMA16(aH,bL,acc2[dt],0,0,0);
        acc2[dt] = MFMA16(aL,bH,acc2[dt],0,0,0);
      }
    }
  }

  // write st partials + snorm
  float* pb = part + ((size_t)bh*64 + chunk)*4160;
  #pragma unroll
  for (int dt=0; dt<2; dt++)
    #pragma unroll
    for (int r=0;r<4;r++){
      int g = gt2*16 + lq*4 + r;
      int d = (dbase+dt)*16 + l15;
      pb[g*64 + d] = acc2[dt][r];
    }
  #pragma unroll
  for (int gt=0; gt<4; gt++)
    #pragma unroll
    for (int r=0;r<4;r++){
      float v = snacc[gt][r];
      v += __shfl_xor(v,1); v += __shfl_xor(v,2);
      v += __shfl_xor(v,4); v += __shfl_xor(v,8);
      if (l15==0) snred[wave*64 + gt*16 + lq*4 + r] = v;
    }
  __syncthreads();
  if (tid < 64){
    float s = 0.f;
    #pragma unroll
    for (int w=0; w<8; w++) s += snred[w*64 + tid];
    pb[4096 + tid] = s;
  }
}

// ---------------------------------------------------------------------------
// K3a: reduce 64 chunk-partials -> stred[bh][4160]. grid (16, 17)
// ---------------------------------------------------------------------------
__global__ __launch_bounds__(256) void k3a_reduce(
    const float* __restrict__ part, float* __restrict__ stred)
{
  const int bh = blockIdx.x;
  const int i = blockIdx.y*256 + threadIdx.x;
  if (i >= 4160) return;
  const float* pb = part + (size_t)bh*64*4160 + i;
  float s[8] = {};
  #pragma unroll 2
  for (int c=0; c<64; c+=8)
    #pragma unroll
    for (int j=0;j<8;j++) s[j] += pb[(size_t)(c+j)*4160];
  stred[bh*4160 + i] = ((s[0]+s[1])+(s[2]+s[3])) + ((s[4]+s[5])+(s[6]+s[7]));
}

// ---------------------------------------------------------------------------
// K3b: per (b,h): st -> SDPA over G=64 -> gate -> Mt[bh][c][g] (transposed!)
// ---------------------------------------------------------------------------
__global__ __launch_bounds__(256) void k3b_slice(
    const float* __restrict__ stred,
    const float* __restrict__ Wq, const float* __restrict__ Wk, const float* __restrict__ Wv,
    const float* __restrict__ Wg1, const float* __restrict__ bg1,
    const float* __restrict__ Wg2, const float* __restrict__ bg2,
    const float* __restrict__ Wo, float* __restrict__ Mt)
{
  const int bh = blockIdx.x;
  const int h = bh & 7;
  const int tid = threadIdx.x;
  __shared__ float st[64][65];
  __shared__ float q[64][65];
  __shared__ float kk[64][65];
  __shared__ float v[64][65];
  __shared__ float attn[64][65];
  __shared__ float outst[64][65];
  __shared__ float h1[64][65];
  __shared__ float sn[64];

  for (int i=tid;i<4160;i+=256){
    float s = stred[bh*4160 + i];
    if (i<4096) st[i>>6][i&63]=s; else sn[i-4096]=s;
  }
  __syncthreads();
  for (int i=tid;i<4096;i+=256){ int g=i>>6,d=i&63; st[g][d] = st[g][d]/(sn[g]+1e-5f); }
  __syncthreads();
  for (int i=tid;i<4096;i+=256){
    int g=i>>6,d=i&63;
    float aq=0,ak=0,av=0;
    for (int c=0;c<64;c++){
      float s=st[g][c];
      aq = fmaf(s, Wq[c*64+d], aq);
      ak = fmaf(s, Wk[c*64+d], ak);
      av = fmaf(s, Wv[c*64+d], av);
    }
    q[g][d]=aq; kk[g][d]=ak; v[g][d]=av;
  }
  __syncthreads();
  for (int i=tid;i<4096;i+=256){
    int g=i>>6,j=i&63; float s=0.f;
    for (int c=0;c<64;c++) s = fmaf(q[g][c], kk[j][c], s);
    attn[g][j]=s*0.125f;
  }
  __syncthreads();
  if (tid<64){
    float mx=-1e30f;
    for(int j=0;j<64;j++) mx=fmaxf(mx,attn[tid][j]);
    float s=0.f;
    for(int j=0;j<64;j++){ float e=__expf(attn[tid][j]-mx); attn[tid][j]=e; s+=e; }
    float invs=1.f/s;
    for(int j=0;j<64;j++) attn[tid][j]*=invs;
  }
  __syncthreads();
  for (int i=tid;i<4096;i+=256){
    int g=i>>6,d=i&63; float s=0.f;
    for (int c=0;c<64;c++) s = fmaf(attn[g][c], v[c][d], s);
    outst[g][d]=s;
  }
  __syncthreads();
  for (int i=tid;i<4096;i+=256){
    int g=i>>6,d=i&63; float s=bg1[d];
    for (int c=0;c<64;c++){
      s = fmaf(st[g][c],    Wg1[c*64+d], s);
      s = fmaf(outst[g][c], Wg1[(64+c)*64+d], s);
    }
    h1[g][d] = s/(1.f+__expf(-s));
  }
  __syncthreads();
  for (int i=tid;i<4096;i+=256){
    int g=i>>6,d=i&63; float s=bg2[d];
    for (int c=0;c<64;c++) s = fmaf(h1[g][c], Wg2[c*64+d], s);
    float gate = 1.f/(1.f+__expf(-s));
    q[g][d] = gate*outst[g][d];
  }
  __syncthreads();
  for (int i=tid;i<16384;i+=256){
    int g=i>>8, c=i&255; float s=0.f;
    for (int d=0;d<64;d++) s = fmaf(q[g][d], Wo[(size_t)(h*64+d)*256 + c], s);
    Mt[(size_t)bh*16384 + c*64 + g] = s;   // transposed: [c][g]
  }
}

// ---------------------------------------------------------------------------
// K4: out[m][c] = sum_h sw_h(m,g) @ M_h(g,c) + bo. Split-bf16 MFMA.
// grid (1024, 2), block 256. Tile 64(m) x 128(c), K = 8h x 64g.
// ---------------------------------------------------------------------------
__global__ __launch_bounds__(256,2) void k4_out(
  const unsigned* __restrict__ swT, const float* __restrict__ Mt,
  const float* __restrict__ bo, float* __restrict__ out)
{
  __shared__ unsigned short AH[64*72], AL[64*72];     // [m][g]
  __shared__ unsigned short BH[128*72], BL[128*72];   // [c][g]
  const int tid = threadIdx.x;
  const int wave = tid>>6, lane = tid&63, l15 = lane&15, lq = lane>>4;
  const int m0 = blockIdx.x*64, c0 = blockIdx.y*128;
  const int b = m0>>15, nn = m0 & 32767;
  f32x4 acc[8] = {};

  for (int hh=0; hh<8; hh++){
    const int bhh = b*8 + hh;
    __syncthreads();
    { // A stage: swT [g][n] packed -> [m][g] hi/lo
      const int g = tid>>2, mq = (tid&3)*16;
      const unsigned* src = swT + ((size_t)bhh*64 + g)*NSEQ + nn + mq;
      #pragma unroll
      for (int i=0;i<4;i++){
        uint4 pv = *(const uint4*)(src + i*4);
        unsigned u[4]={pv.x,pv.y,pv.z,pv.w};
        #pragma unroll
        for (int j=0;j<4;j++){
          int m = mq + i*4 + j;
          AH[m*72+g] = (unsigned short)(u[j] & 0xFFFFu);
          AL[m*72+g] = (unsigned short)(u[j] >> 16);
        }
      }
      // B stage: Mt [c][g] fp32 -> split
      const int c = tid>>1, gq = (tid&1)*32;
      const float* bsrc = Mt + (size_t)bhh*16384 + (size_t)(c0+c)*64 + gq;
      #pragma unroll
      for (int i=0;i<8;i++){
        float4 v = *(const float4*)(bsrc + i*4);
        float vv[4]={v.x,v.y,v.z,v.w};
        ushort4 hh4, ll4;
        unsigned short* hp=(unsigned short*)&hh4; unsigned short* lp=(unsigned short*)&ll4;
        #pragma unroll
        for (int j=0;j<4;j++) split2(vv[j], &hp[j], &lp[j]);
        *(ushort4*)&BH[c*72 + gq + i*4] = hh4;
        *(ushort4*)&BL[c*72 + gq + i*4] = ll4;
      }
    }
    __syncthreads();
    #pragma unroll
    for (int ks=0; ks<2; ks++){
      const int koff = ks*32 + lq*8;
      short8v aH = *(const short8v*)&AH[(wave*16+l15)*72 + koff];
      short8v aL = *(const short8v*)&AL[(wave*16+l15)*72 + koff];
      #pragma unroll
      for (int ct=0; ct<8; ct++){
        short8v bH = *(const short8v*)&BH[(ct*16+l15)*72 + koff];
        short8v bL = *(const short8v*)&BL[(ct*16+l15)*72 + koff];
        acc[ct] = MFMA16(aH,bH,acc[ct],0,0,0);
        acc[ct] = MFMA16(aH,bL,acc[ct],0,0,0);
        acc[ct] = MFMA16(aL,bH,acc[ct],0,0,0);
      }
    }
  }
  #pragma unroll
  for (int ct=0; ct<8; ct++)
    #pragma unroll
    for (int r=0;r<4;r++){
      int c = c0 + ct*16 + l15;
      out[(size_t)(m0 + wave*16 + lq*4 + r)*256 + c] = acc[ct][r] + bo[c];
    }
}

// ---------------------------------------------------------------------------
extern "C" void kernel_launch(void* const* d_in, const int* in_sizes, int n_in,
                              void* d_out, int out_size, void* d_ws, size_t ws_size,
                              hipStream_t stream) {
  (void)in_sizes; (void)n_in; (void)out_size;
  const float* x    = (const float*)d_in[0];
  const float* pos  = (const float*)d_in[1];
  const float* gum  = (const float*)d_in[2];
  const float* Wx   = (const float*)d_in[3];
  const float* bx   = (const float*)d_in[4];
  const float* W1   = (const float*)d_in[5];
  const float* b1   = (const float*)d_in[6];
  const float* W2   = (const float*)d_in[7];
  const float* b2   = (const float*)d_in[8];
  const float* bias = (const float*)d_in[9];
  const float* Wr   = (const float*)d_in[10];
  const float* br   = (const float*)d_in[11];
  const float* Ws   = (const float*)d_in[12];
  const float* bs   = (const float*)d_in[13];
  const float* Wq   = (const float*)d_in[14];
  const float* Wk   = (const float*)d_in[15];
  const float* Wv   = (const float*)d_in[16];
  const float* Wg1  = (const float*)d_in[17];
  const float* bg1  = (const float*)d_in[18];
  const float* Wg2  = (const float*)d_in[19];
  const float* bg2  = (const float*)d_in[20];
  const float* Wo   = (const float*)d_in[21];
  const float* bo   = (const float*)d_in[22];
  float* out = (float*)d_out;

  // workspace (floats): xmid 33554432 | swT 33554432 (uint) | part 4259840 | stred 66560
  float*    xmid  = (float*)d_ws;
  unsigned* swT   = (unsigned*)(xmid + (size_t)33554432);
  float*    partp = (float*)(swT + (size_t)33554432);
  float*    stred = partp + (size_t)4259840;
  float*    Mt    = partp;  // alias: part is dead after k3a
  const size_t need = ((size_t)33554432*2 + 4259840 + 66560) * 4;
  if (ws_size < need) return;

  k1_gemm_rope<<<dim3(1024,8), 256, 0, stream>>>(x, pos, Wx, bx, Wr, br, xmid);
  k2_tile<<<dim3(64,16), 512, 0, stream>>>(xmid, gum, W1, b1, W2, b2, bias, Ws, bs, swT, partp);
  k3a_reduce<<<dim3(16,17), 256, 0, stream>>>(partp, stred);
  k3b_slice<<<16, 256, 0, stream>>>(stred, Wq, Wk, Wv, Wg1, bg1, Wg2, bg2, Wo, Mt);
  k4_out<<<dim3(1024,2), 256, 0, stream>>>(swT, Mt, bo, out);
}

// Round 5
// 538.547 us; speedup vs baseline: 4.6019x; 1.2653x over previous
//
#include <hip/hip_runtime.h>
#include <math.h>

#define NSEQ 32768

using short8v = __attribute__((ext_vector_type(8))) short;
using f32x4   = __attribute__((ext_vector_type(4))) float;
#define MFMA16 __builtin_amdgcn_mfma_f32_16x16x32_bf16

__device__ __forceinline__ unsigned short f2bf(float f){
  union{float f; unsigned u;} v; v.f = f;
  return (unsigned short)((v.u + 0x7FFFu + ((v.u>>16)&1u))>>16);
}
__device__ __forceinline__ float bf2f(unsigned short h){
  union{unsigned u; float f;} v; v.u = ((unsigned)h)<<16; return v.f;
}
__device__ __forceinline__ void split2(float f, unsigned short* h, unsigned short* l){
  unsigned short hh = f2bf(f);
  *h = hh; *l = f2bf(f - bf2f(hh));
}
__device__ __forceinline__ float gelu_f(float x){
  return 0.5f*x*(1.f + erff(x*0.70710678118654752f));
}

// ---------------------------------------------------------------------------
// K0: Wx [256][512] fp32 -> WxTH/WxTL [512][256] split-bf16 (transposed). Once.
// ---------------------------------------------------------------------------
__global__ __launch_bounds__(256) void k0_prep(const float* __restrict__ Wx,
    unsigned short* __restrict__ WxTH, unsigned short* __restrict__ WxTL)
{
  const int n = blockIdx.x;     // 0..511
  const int k = threadIdx.x;    // 0..255
  float v = Wx[(size_t)k*512 + n];
  unsigned short hh, ll; split2(v,&hh,&ll);
  WxTH[n*256+k]=hh; WxTL[n*256+k]=ll;
}

// ---------------------------------------------------------------------------
// K1 v2: xmid[b,h,n,d] = (x @ Wx + bx)[b,n,h*64+d] + rope.
// grid 512 blocks x 512 threads. Block = 128 tokens x all 512 cols.
// x staged+split once; A-frags held in registers across all heads.
// B panels copied from precomputed WxT (pure 16B copies).
// LDS XOR granule swizzle: 256B rows, granule g stored at g^(row&15).
// ---------------------------------------------------------------------------
__global__ __launch_bounds__(512,1) void k1_gemm_rope(
    const float* __restrict__ x, const float* __restrict__ pos,
    const unsigned short* __restrict__ WxTH, const unsigned short* __restrict__ WxTL,
    const float* __restrict__ bx,
    const float* __restrict__ Wr, const float* __restrict__ br,
    float* __restrict__ xmid)
{
  __shared__ unsigned short SA[2*128*128];  // hi plane, lo plane; [row][128k] swizzled
  __shared__ unsigned short SB[2*64*128];   // hi, lo
  __shared__ float trig[128][8];
  const int tid = threadIdx.x;
  const int wave = tid>>6, lane = tid&63, l15 = lane&15, lq = lane>>4;
  const int m0 = blockIdx.x*128;

  // trig per token (once)
  if (tid < 128){
    int m = m0 + tid;
    float a0 = pos[m*3+0];
    float a1 = pos[m*3+1] * 0.046415888336127774f;  // 10000^(-1/3)
    float a2 = pos[m*3+2] * 0.002154434690031884f;  // 10000^(-2/3)
    trig[tid][0]=sinf(a0); trig[tid][1]=sinf(a1); trig[tid][2]=sinf(a2);
    trig[tid][3]=cosf(a0); trig[tid][4]=cosf(a1); trig[tid][5]=cosf(a2);
  }

  // Stage x (split-bf16) one k-half at a time; preload A-frags to registers.
  short8v aHr[8], aLr[8];
  {
    const int lm = tid>>2, lkq = (tid&3)*32;   // row 0..127, k-offset in half
    #pragma unroll
    for (int kh=0; kh<2; kh++){
      __syncthreads();
      const float* src = x + (size_t)(m0+lm)*256 + kh*128 + lkq;
      #pragma unroll
      for (int i=0;i<8;i++){
        float4 v = *(const float4*)(src + i*4);
        ushort4 hh, ll;
        split2(v.x,&hh.x,&ll.x); split2(v.y,&hh.y,&ll.y);
        split2(v.z,&hh.z,&ll.z); split2(v.w,&hh.w,&ll.w);
        int G = (lkq>>3) + (i>>1);
        int idx = lm*128 + (((G ^ (lm&15)))<<3) + ((i&1)<<2);
        *(ushort4*)&SA[idx] = hh;
        *(ushort4*)&SA[128*128 + idx] = ll;
      }
      __syncthreads();
      const int row = wave*16 + l15;
      #pragma unroll
      for (int ks=0; ks<4; ks++){
        int idx = row*128 + ((((ks<<2)+lq) ^ l15)<<3);
        aHr[kh*4+ks] = *(const short8v*)&SA[idx];
        aLr[kh*4+ks] = *(const short8v*)&SA[128*128 + idx];
      }
    }
  }

  // rope values this thread needs: tokens wave*16+lq*4+r, cols j*16+l15
  float ropev[4][4];
  #pragma unroll
  for (int r=0;r<4;r++){
    int tk = wave*16 + lq*4 + r;
    float t0=trig[tk][0],t1=trig[tk][1],t2=trig[tk][2];
    float t3=trig[tk][3],t4=trig[tk][4],t5=trig[tk][5];
    #pragma unroll
    for (int j=0;j<4;j++){
      int d = j*16 + l15;
      float v = br[d];
      v = fmaf(t0, Wr[0*64+d], v);
      v = fmaf(t1, Wr[1*64+d], v);
      v = fmaf(t2, Wr[2*64+d], v);
      v = fmaf(t3, Wr[3*64+d], v);
      v = fmaf(t4, Wr[4*64+d], v);
      v = fmaf(t5, Wr[5*64+d], v);
      ropev[r][j] = v;
    }
  }

  const int bidx = m0 >> 15;
  const int nbase = (m0 & 32767) + wave*16 + lq*4;
  const int ln = tid>>3, lnkq = (tid&7)*16;   // B-copy: row 0..63, 16 ushorts

  for (int h=0; h<8; h++){
    f32x4 acc[4] = {};
    #pragma unroll
    for (int kh=0; kh<2; kh++){
      __syncthreads();
      { // copy B panel: WxT rows h*64+ln, k-cols kh*128+lnkq .. +16
        const unsigned short* sH = WxTH + (size_t)(h*64+ln)*256 + kh*128 + lnkq;
        const unsigned short* sL = WxTL + (size_t)(h*64+ln)*256 + kh*128 + lnkq;
        int g0 = lnkq>>3;
        int i0 = ln*128 + ((g0     ^ (ln&15))<<3);
        int i1 = ln*128 + (((g0+1) ^ (ln&15))<<3);
        *(uint4*)&SB[i0] = *(const uint4*)sH;
        *(uint4*)&SB[i1] = *(const uint4*)(sH+8);
        *(uint4*)&SB[64*128 + i0] = *(const uint4*)sL;
        *(uint4*)&SB[64*128 + i1] = *(const uint4*)(sL+8);
      }
      __syncthreads();
      #pragma unroll
      for (int ks=0; ks<4; ks++){
        short8v a_h = aHr[kh*4+ks], a_l = aLr[kh*4+ks];
        #pragma unroll
        for (int j=0;j<4;j++){
          int idx = (j*16+l15)*128 + ((((ks<<2)+lq) ^ l15)<<3);
          short8v b_h = *(const short8v*)&SB[idx];
          short8v b_l = *(const short8v*)&SB[64*128 + idx];
          acc[j] = MFMA16(a_h,b_h,acc[j],0,0,0);
          acc[j] = MFMA16(a_h,b_l,acc[j],0,0,0);
          acc[j] = MFMA16(a_l,b_h,acc[j],0,0,0);
        }
      }
    }
    // write head h
    #pragma unroll
    for (int j=0;j<4;j++){
      int col = j*16 + l15;
      float bxv = bx[h*64+col];
      #pragma unroll
      for (int r=0;r<4;r++){
        xmid[(((size_t)(bidx*8+h))*NSEQ + nbase + r)*64 + col] =
          acc[j][r] + bxv + ropev[r][j];
      }
    }
  }
}

// ---------------------------------------------------------------------------
// K2: per (bh, 512-token chunk), 512 threads (8 waves), subtiles of 128 tokens.
// ---------------------------------------------------------------------------
__global__ __launch_bounds__(512,1) void k2_tile(
  const float* __restrict__ xmid, const float* __restrict__ gum,
  const float* __restrict__ W1, const float* __restrict__ b1,
  const float* __restrict__ W2, const float* __restrict__ b2,
  const float* __restrict__ biasp,
  const float* __restrict__ Ws, const float* __restrict__ bs,
  unsigned* __restrict__ swT, float* __restrict__ part)
{
  __shared__ unsigned short XAh[128*72], XAl[128*72];   // [m][d]
  __shared__ unsigned short XBh[64*136], XBl[64*136];   // [d][m]
  __shared__ unsigned short W1h[64*72], W1l[64*72];     // [g][d]
  __shared__ unsigned short Wsh[64*72], Wsl[64*72];
  __shared__ unsigned short swh[64*136], swl[64*136];   // [g][m]
  __shared__ float snred[8*64];
  __shared__ float prm[200];

  const int tid = threadIdx.x;
  const int wave = tid>>6, lane = tid&63, l15 = lane&15, lq = lane>>4;
  const int bh = blockIdx.y, chunk = blockIdx.x, h = bh&7;
  const size_t rowbase = (size_t)bh*NSEQ;

  { // stage weights transposed + params
    const int ld = tid>>3, lg8 = (tid&7)*8;
    #pragma unroll
    for (int i=0;i<2;i++){
      float4 v1 = *(const float4*)(W1 + ld*64 + lg8 + i*4);
      float4 vs = *(const float4*)(Ws + ld*64 + lg8 + i*4);
      float a1[4]={v1.x,v1.y,v1.z,v1.w}, as[4]={vs.x,vs.y,vs.z,vs.w};
      #pragma unroll
      for (int j=0;j<4;j++){
        unsigned short hh,ll;
        split2(a1[j],&hh,&ll);
        W1h[(lg8+i*4+j)*72+ld]=hh; W1l[(lg8+i*4+j)*72+ld]=ll;
        split2(as[j],&hh,&ll);
        Wsh[(lg8+i*4+j)*72+ld]=hh; Wsl[(lg8+i*4+j)*72+ld]=ll;
      }
    }
    if (tid<64){ prm[tid]=b1[tid]; prm[64+tid]=bs[tid]; prm[128+tid]=W2[tid]; }
    if (tid==64){ prm[192]=b2[0]; prm[193]=biasp[h]; }
  }

  f32x4 acc2[2] = {};
  float snacc[4][4] = {};
  const int gt2 = wave>>1, dbase = (wave&1)*2;

  for (int sub=0; sub<4; ++sub){
    const int n0 = chunk*512 + sub*128;
    __syncthreads();
    { // stage XA [m][d] and XB [d][m] (split)
      const int lm = tid>>2, ldq = (tid&3)*16;
      const float* src = xmid + (rowbase + n0 + lm)*64 + ldq;
      #pragma unroll
      for (int i=0;i<4;i++){
        float4 v = *(const float4*)(src + i*4);
        float vv[4]={v.x,v.y,v.z,v.w};
        ushort4 hh, ll;
        unsigned short* hp=(unsigned short*)&hh; unsigned short* lp=(unsigned short*)&ll;
        #pragma unroll
        for (int j=0;j<4;j++) split2(vv[j], &hp[j], &lp[j]);
        *(ushort4*)&XAh[lm*72 + ldq + i*4] = hh;
        *(ushort4*)&XAl[lm*72 + ldq + i*4] = ll;
        #pragma unroll
        for (int j=0;j<4;j++){
          XBh[(ldq+i*4+j)*136 + lm] = hp[j];
          XBl[(ldq+i*4+j)*136 + lm] = lp[j];
        }
      }
    }
    __syncthreads();

    const int mloc = wave*16 + l15;
    const float* grow = gum + (rowbase + n0 + mloc)*64;
    float gu[4][4];
    #pragma unroll
    for (int gt=0; gt<4; gt++)
      #pragma unroll
      for (int r=0;r<4;r++) gu[gt][r] = grow[gt*16 + lq*4 + r];

    // GEMM1': D1[g][m], A=W^T [g][d], B=X [m][d]
    f32x4 t1a[4] = {}, lga[4] = {};
    #pragma unroll
    for (int ks=0; ks<2; ks++){
      const int koff = ks*32 + lq*8;
      short8v xH = *(const short8v*)&XAh[(wave*16+l15)*72 + koff];
      short8v xL = *(const short8v*)&XAl[(wave*16+l15)*72 + koff];
      #pragma unroll
      for (int gt=0; gt<4; gt++){
        const int aoff = (gt*16+l15)*72 + koff;
        short8v wH = *(const short8v*)&W1h[aoff];
        short8v wL = *(const short8v*)&W1l[aoff];
        t1a[gt] = MFMA16(wH,xH,t1a[gt],0,0,0);
        t1a[gt] = MFMA16(wH,xL,t1a[gt],0,0,0);
        t1a[gt] = MFMA16(wL,xH,t1a[gt],0,0,0);
        short8v sH = *(const short8v*)&Wsh[aoff];
        short8v sL = *(const short8v*)&Wsl[aoff];
        lga[gt] = MFMA16(sH,xH,lga[gt],0,0,0);
        lga[gt] = MFMA16(sH,xL,lga[gt],0,0,0);
        lga[gt] = MFMA16(sL,xH,lga[gt],0,0,0);
      }
    }

    // temperature (per token = per lane)
    float p = 0.f;
    #pragma unroll
    for (int gt=0; gt<4; gt++)
      #pragma unroll
      for (int r=0;r<4;r++){
        int g = gt*16 + lq*4 + r;
        p += gelu_f(t1a[gt][r] + prm[g]) * prm[128+g];
      }
    p += __shfl_xor(p,16); p += __shfl_xor(p,32);
    float t2 = gelu_f(p + prm[192]);
    float rtemp = 1.f / fmaxf(t2 + prm[193], 0.01f);

    // gumbel softmax over g
    float z[4][4]; float mx = -1e30f;
    #pragma unroll
    for (int gt=0; gt<4; gt++)
      #pragma unroll
      for (int r=0;r<4;r++){
        int g = gt*16 + lq*4 + r;
        float gn = -__logf(-__logf(gu[gt][r]+1e-8f)+1e-8f);
        float zz = (lga[gt][r] + prm[64+g] + gn)*rtemp;
        z[gt][r]=zz; mx = fmaxf(mx, zz);
      }
    mx = fmaxf(mx, __shfl_xor(mx,16)); mx = fmaxf(mx, __shfl_xor(mx,32));
    float se = 0.f;
    #pragma unroll
    for (int gt=0; gt<4; gt++)
      #pragma unroll
      for (int r=0;r<4;r++){ float e = __expf(z[gt][r]-mx); z[gt][r]=e; se += e; }
    se += __shfl_xor(se,16); se += __shfl_xor(se,32);
    float inv = 1.f/se;
    #pragma unroll
    for (int gt=0; gt<4; gt++)
      #pragma unroll
      for (int r=0;r<4;r++){
        float swv = z[gt][r]*inv;
        snacc[gt][r] += swv;
        int g = gt*16 + lq*4 + r;
        unsigned short hh,ll; split2(swv,&hh,&ll);
        swh[g*136 + mloc] = hh; swl[g*136 + mloc] = ll;
      }
    __syncthreads();

    { // write sw to global as packed (hi | lo<<16), layout [bh][g][n]
      const int g = tid>>3, mq = (tid&7)*16;
      #pragma unroll
      for (int i=0;i<4;i++){
        ushort4 hh = *(const ushort4*)&swh[g*136 + mq + i*4];
        ushort4 ll = *(const ushort4*)&swl[g*136 + mq + i*4];
        uint4 pk;
        pk.x = (unsigned)hh.x | ((unsigned)ll.x<<16);
        pk.y = (unsigned)hh.y | ((unsigned)ll.y<<16);
        pk.z = (unsigned)hh.z | ((unsigned)ll.z<<16);
        pk.w = (unsigned)hh.w | ((unsigned)ll.w<<16);
        *(uint4*)(swT + ((size_t)bh*64 + g)*NSEQ + n0 + mq + i*4) = pk;
      }
    }

    // st-GEMM: D2[g][d] += sw^T X, A=sw [g][m], B=X [d][m]
    #pragma unroll
    for (int ks=0; ks<4; ks++){
      const int koff = ks*32 + lq*8;
      short8v aH = *(const short8v*)&swh[(gt2*16+l15)*136 + koff];
      short8v aL = *(const short8v*)&swl[(gt2*16+l15)*136 + koff];
      #pragma unroll
      for (int dt=0; dt<2; dt++){
        const int boff = ((dbase+dt)*16+l15)*136 + koff;
        short8v bH = *(const short8v*)&XBh[boff];
        short8v bL = *(const short8v*)&XBl[boff];
        acc2[dt] = MFMA16(aH,bH,acc2[dt],0,0,0);
        acc2[dt] = MFMA16(aH,bL,acc2[dt],0,0,0);
        acc2[dt] = MFMA16(aL,bH,acc2[dt],0,0,0);
      }
    }
  }

  // write st partials + snorm
  float* pb = part + ((size_t)bh*64 + chunk)*4160;
  #pragma unroll
  for (int dt=0; dt<2; dt++)
    #pragma unroll
    for (int r=0;r<4;r++){
      int g = gt2*16 + lq*4 + r;
      int d = (dbase+dt)*16 + l15;
      pb[g*64 + d] = acc2[dt][r];
    }
  #pragma unroll
  for (int gt=0; gt<4; gt++)
    #pragma unroll
    for (int r=0;r<4;r++){
      float v = snacc[gt][r];
      v += __shfl_xor(v,1); v += __shfl_xor(v,2);
      v += __shfl_xor(v,4); v += __shfl_xor(v,8);
      if (l15==0) snred[wave*64 + gt*16 + lq*4 + r] = v;
    }
  __syncthreads();
  if (tid < 64){
    float s = 0.f;
    #pragma unroll
    for (int w=0; w<8; w++) s += snred[w*64 + tid];
    pb[4096 + tid] = s;
  }
}

// ---------------------------------------------------------------------------
// K3a: reduce 64 chunk-partials -> stred[bh][4160]. grid (16, 17)
// ---------------------------------------------------------------------------
__global__ __launch_bounds__(256) void k3a_reduce(
    const float* __restrict__ part, float* __restrict__ stred)
{
  const int bh = blockIdx.x;
  const int i = blockIdx.y*256 + threadIdx.x;
  if (i >= 4160) return;
  const float* pb = part + (size_t)bh*64*4160 + i;
  float s[8] = {};
  #pragma unroll 2
  for (int c=0; c<64; c+=8)
    #pragma unroll
    for (int j=0;j<8;j++) s[j] += pb[(size_t)(c+j)*4160];
  stred[bh*4160 + i] = ((s[0]+s[1])+(s[2]+s[3])) + ((s[4]+s[5])+(s[6]+s[7]));
}

// ---------------------------------------------------------------------------
// K3b: per (b,h): st -> SDPA over G=64 -> gate -> Mt[bh][c][g] (transposed!)
// ---------------------------------------------------------------------------
__global__ __launch_bounds__(256) void k3b_slice(
    const float* __restrict__ stred,
    const float* __restrict__ Wq, const float* __restrict__ Wk, const float* __restrict__ Wv,
    const float* __restrict__ Wg1, const float* __restrict__ bg1,
    const float* __restrict__ Wg2, const float* __restrict__ bg2,
    const float* __restrict__ Wo, float* __restrict__ Mt)
{
  const int bh = blockIdx.x;
  const int h = bh & 7;
  const int tid = threadIdx.x;
  __shared__ float st[64][65];
  __shared__ float q[64][65];
  __shared__ float kk[64][65];
  __shared__ float v[64][65];
  __shared__ float attn[64][65];
  __shared__ float outst[64][65];
  __shared__ float h1[64][65];
  __shared__ float sn[64];

  for (int i=tid;i<4160;i+=256){
    float s = stred[bh*4160 + i];
    if (i<4096) st[i>>6][i&63]=s; else sn[i-4096]=s;
  }
  __syncthreads();
  for (int i=tid;i<4096;i+=256){ int g=i>>6,d=i&63; st[g][d] = st[g][d]/(sn[g]+1e-5f); }
  __syncthreads();
  for (int i=tid;i<4096;i+=256){
    int g=i>>6,d=i&63;
    float aq=0,ak=0,av=0;
    for (int c=0;c<64;c++){
      float s=st[g][c];
      aq = fmaf(s, Wq[c*64+d], aq);
      ak = fmaf(s, Wk[c*64+d], ak);
      av = fmaf(s, Wv[c*64+d], av);
    }
    q[g][d]=aq; kk[g][d]=ak; v[g][d]=av;
  }
  __syncthreads();
  for (int i=tid;i<4096;i+=256){
    int g=i>>6,j=i&63; float s=0.f;
    for (int c=0;c<64;c++) s = fmaf(q[g][c], kk[j][c], s);
    attn[g][j]=s*0.125f;
  }
  __syncthreads();
  if (tid<64){
    float mx=-1e30f;
    for(int j=0;j<64;j++) mx=fmaxf(mx,attn[tid][j]);
    float s=0.f;
    for(int j=0;j<64;j++){ float e=__expf(attn[tid][j]-mx); attn[tid][j]=e; s+=e; }
    float invs=1.f/s;
    for(int j=0;j<64;j++) attn[tid][j]*=invs;
  }
  __syncthreads();
  for (int i=tid;i<4096;i+=256){
    int g=i>>6,d=i&63; float s=0.f;
    for (int c=0;c<64;c++) s = fmaf(attn[g][c], v[c][d], s);
    outst[g][d]=s;
  }
  __syncthreads();
  for (int i=tid;i<4096;i+=256){
    int g=i>>6,d=i&63; float s=bg1[d];
    for (int c=0;c<64;c++){
      s = fmaf(st[g][c],    Wg1[c*64+d], s);
      s = fmaf(outst[g][c], Wg1[(64+c)*64+d], s);
    }
    h1[g][d] = s/(1.f+__expf(-s));
  }
  __syncthreads();
  for (int i=tid;i<4096;i+=256){
    int g=i>>6,d=i&63; float s=bg2[d];
    for (int c=0;c<64;c++) s = fmaf(h1[g][c], Wg2[c*64+d], s);
    float gate = 1.f/(1.f+__expf(-s));
    q[g][d] = gate*outst[g][d];
  }
  __syncthreads();
  for (int i=tid;i<16384;i+=256){
    int g=i>>8, c=i&255; float s=0.f;
    for (int d=0;d<64;d++) s = fmaf(q[g][d], Wo[(size_t)(h*64+d)*256 + c], s);
    Mt[(size_t)bh*16384 + c*64 + g] = s;   // transposed: [c][g]
  }
}

// ---------------------------------------------------------------------------
// K4: out[m][c] = sum_h sw_h(m,g) @ M_h(g,c) + bo. Split-bf16 MFMA.
// ---------------------------------------------------------------------------
__global__ __launch_bounds__(256,2) void k4_out(
  const unsigned* __restrict__ swT, const float* __restrict__ Mt,
  const float* __restrict__ bo, float* __restrict__ out)
{
  __shared__ unsigned short AH[64*72], AL[64*72];     // [m][g]
  __shared__ unsigned short BH[128*72], BL[128*72];   // [c][g]
  const int tid = threadIdx.x;
  const int wave = tid>>6, lane = tid&63, l15 = lane&15, lq = lane>>4;
  const int m0 = blockIdx.x*64, c0 = blockIdx.y*128;
  const int b = m0>>15, nn = m0 & 32767;
  f32x4 acc[8] = {};

  for (int hh=0; hh<8; hh++){
    const int bhh = b*8 + hh;
    __syncthreads();
    { // A stage: swT [g][n] packed -> [m][g] hi/lo
      const int g = tid>>2, mq = (tid&3)*16;
      const unsigned* src = swT + ((size_t)bhh*64 + g)*NSEQ + nn + mq;
      #pragma unroll
      for (int i=0;i<4;i++){
        uint4 pv = *(const uint4*)(src + i*4);
        unsigned u[4]={pv.x,pv.y,pv.z,pv.w};
        #pragma unroll
        for (int j=0;j<4;j++){
          int m = mq + i*4 + j;
          AH[m*72+g] = (unsigned short)(u[j] & 0xFFFFu);
          AL[m*72+g] = (unsigned short)(u[j] >> 16);
        }
      }
      // B stage: Mt [c][g] fp32 -> split
      const int c = tid>>1, gq = (tid&1)*32;
      const float* bsrc = Mt + (size_t)bhh*16384 + (size_t)(c0+c)*64 + gq;
      #pragma unroll
      for (int i=0;i<8;i++){
        float4 v = *(const float4*)(bsrc + i*4);
        float vv[4]={v.x,v.y,v.z,v.w};
        ushort4 hh4, ll4;
        unsigned short* hp=(unsigned short*)&hh4; unsigned short* lp=(unsigned short*)&ll4;
        #pragma unroll
        for (int j=0;j<4;j++) split2(vv[j], &hp[j], &lp[j]);
        *(ushort4*)&BH[c*72 + gq + i*4] = hh4;
        *(ushort4*)&BL[c*72 + gq + i*4] = ll4;
      }
    }
    __syncthreads();
    #pragma unroll
    for (int ks=0; ks<2; ks++){
      const int koff = ks*32 + lq*8;
      short8v aH = *(const short8v*)&AH[(wave*16+l15)*72 + koff];
      short8v aL = *(const short8v*)&AL[(wave*16+l15)*72 + koff];
      #pragma unroll
      for (int ct=0; ct<8; ct++){
        short8v bH = *(const short8v*)&BH[(ct*16+l15)*72 + koff];
        short8v bL = *(const short8v*)&BL[(ct*16+l15)*72 + koff];
        acc[ct] = MFMA16(aH,bH,acc[ct],0,0,0);
        acc[ct] = MFMA16(aH,bL,acc[ct],0,0,0);
        acc[ct] = MFMA16(aL,bH,acc[ct],0,0,0);
      }
    }
  }
  #pragma unroll
  for (int ct=0; ct<8; ct++)
    #pragma unroll
    for (int r=0;r<4;r++){
      int c = c0 + ct*16 + l15;
      out[(size_t)(m0 + wave*16 + lq*4 + r)*256 + c] = acc[ct][r] + bo[c];
    }
}

// ---------------------------------------------------------------------------
extern "C" void kernel_launch(void* const* d_in, const int* in_sizes, int n_in,
                              void* d_out, int out_size, void* d_ws, size_t ws_size,
                              hipStream_t stream) {
  (void)in_sizes; (void)n_in; (void)out_size;
  const float* x    = (const float*)d_in[0];
  const float* pos  = (const float*)d_in[1];
  const float* gum  = (const float*)d_in[2];
  const float* Wx   = (const float*)d_in[3];
  const float* bx   = (const float*)d_in[4];
  const float* W1   = (const float*)d_in[5];
  const float* b1   = (const float*)d_in[6];
  const float* W2   = (const float*)d_in[7];
  const float* b2   = (const float*)d_in[8];
  const float* bias = (const float*)d_in[9];
  const float* Wr   = (const float*)d_in[10];
  const float* br   = (const float*)d_in[11];
  const float* Ws   = (const float*)d_in[12];
  const float* bs   = (const float*)d_in[13];
  const float* Wq   = (const float*)d_in[14];
  const float* Wk   = (const float*)d_in[15];
  const float* Wv   = (const float*)d_in[16];
  const float* Wg1  = (const float*)d_in[17];
  const float* bg1  = (const float*)d_in[18];
  const float* Wg2  = (const float*)d_in[19];
  const float* bg2  = (const float*)d_in[20];
  const float* Wo   = (const float*)d_in[21];
  const float* bo   = (const float*)d_in[22];
  float* out = (float*)d_out;

  // ws (floats): xmid 33554432 | swT 33554432 (uint) | part 4259840 | stred 66560 | WxT 65536
  float*    xmid  = (float*)d_ws;
  unsigned* swT   = (unsigned*)(xmid + (size_t)33554432);
  float*    partp = (float*)(swT + (size_t)33554432);
  float*    stred = partp + (size_t)4259840;
  unsigned short* WxTH = (unsigned short*)(stred + (size_t)66560);
  unsigned short* WxTL = WxTH + (size_t)131072;
  float*    Mt    = partp;  // alias: part is dead after k3a
  const size_t need = ((size_t)33554432*2 + 4259840 + 66560)*4 + (size_t)131072*2*2;
  if (ws_size < need) return;

  k0_prep<<<512, 256, 0, stream>>>(Wx, WxTH, WxTL);
  k1_gemm_rope<<<512, 512, 0, stream>>>(x, pos, WxTH, WxTL, bx, Wr, br, xmid);
  k2_tile<<<dim3(64,16), 512, 0, stream>>>(xmid, gum, W1, b1, W2, b2, bias, Ws, bs, swT, partp);
  k3a_reduce<<<dim3(16,17), 256, 0, stream>>>(partp, stred);
  k3b_slice<<<16, 256, 0, stream>>>(stred, Wq, Wk, Wv, Wg1, bg1, Wg2, bg2, Wo, Mt);
  k4_out<<<dim3(1024,2), 256, 0, stream>>>(swT, Mt, bo, out);
}

// Round 6
// 479.610 us; speedup vs baseline: 5.1674x; 1.1229x over previous
//
#include <hip/hip_runtime.h>
#include <math.h>

#define NSEQ 32768

using short8v = __attribute__((ext_vector_type(8))) short;
using f32x4   = __attribute__((ext_vector_type(4))) float;
#define MFMA16 __builtin_amdgcn_mfma_f32_16x16x32_bf16

__device__ __forceinline__ unsigned short f2bf(float f){
  union{float f; unsigned u;} v; v.f = f;
  return (unsigned short)((v.u + 0x7FFFu + ((v.u>>16)&1u))>>16);
}
__device__ __forceinline__ float bf2f(unsigned short h){
  union{unsigned u; float f;} v; v.u = ((unsigned)h)<<16; return v.f;
}
__device__ __forceinline__ void split2(float f, unsigned short* h, unsigned short* l){
  unsigned short hh = f2bf(f);
  *h = hh; *l = f2bf(f - bf2f(hh));
}
__device__ __forceinline__ float gelu_f(float x){
  return 0.5f*x*(1.f + erff(x*0.70710678118654752f));
}

// ---------------------------------------------------------------------------
// K0: Wx [256][512] fp32 -> WxTH/WxTL [512][256] split-bf16 (transposed). Once.
// ---------------------------------------------------------------------------
__global__ __launch_bounds__(256) void k0_prep(const float* __restrict__ Wx,
    unsigned short* __restrict__ WxTH, unsigned short* __restrict__ WxTL)
{
  const int n = blockIdx.x;     // 0..511
  const int k = threadIdx.x;    // 0..255
  float v = Wx[(size_t)k*512 + n];
  unsigned short hh, ll; split2(v,&hh,&ll);
  WxTH[n*256+k]=hh; WxTL[n*256+k]=ll;
}

// ---------------------------------------------------------------------------
// K0b: prep all small weights as transposed split-bf16. grid 11 x 256.
// ---------------------------------------------------------------------------
__global__ __launch_bounds__(256) void k0b_prep(
  const float* __restrict__ Wq, const float* __restrict__ Wk, const float* __restrict__ Wv,
  const float* __restrict__ Wg1, const float* __restrict__ Wg2, const float* __restrict__ Wo,
  const float* __restrict__ W1, const float* __restrict__ Ws,
  unsigned short* __restrict__ WqTH, unsigned short* __restrict__ WqTL,
  unsigned short* __restrict__ WkTH, unsigned short* __restrict__ WkTL,
  unsigned short* __restrict__ WvTH, unsigned short* __restrict__ WvTL,
  unsigned short* __restrict__ Wg1TH, unsigned short* __restrict__ Wg1TL,
  unsigned short* __restrict__ Wg2TH, unsigned short* __restrict__ Wg2TL,
  unsigned short* __restrict__ WoTH, unsigned short* __restrict__ WoTL,
  unsigned short* __restrict__ W1TH, unsigned short* __restrict__ W1TL,
  unsigned short* __restrict__ WsTH, unsigned short* __restrict__ WsTL)
{
  const int bx = blockIdx.x, t = threadIdx.x;
  unsigned short hh, ll;
  if (bx == 0){
    for (int i=0;i<16;i++){ int idx=i*256+t; int r=idx>>6, c=idx&63;
      split2(Wq[r*64+c],&hh,&ll); WqTH[c*64+r]=hh; WqTL[c*64+r]=ll;
      split2(Wk[r*64+c],&hh,&ll); WkTH[c*64+r]=hh; WkTL[c*64+r]=ll;
      split2(Wv[r*64+c],&hh,&ll); WvTH[c*64+r]=hh; WvTL[c*64+r]=ll;
    }
  } else if (bx == 1){
    for (int i=0;i<32;i++){ int idx=i*256+t; int r=idx>>6, c=idx&63;  // r=c2, c=d
      split2(Wg1[r*64+c],&hh,&ll); Wg1TH[c*128+r]=hh; Wg1TL[c*128+r]=ll;
    }
  } else if (bx == 2){
    for (int i=0;i<16;i++){ int idx=i*256+t; int r=idx>>6, c=idx&63;
      split2(Wg2[r*64+c],&hh,&ll); Wg2TH[c*64+r]=hh; Wg2TL[c*64+r]=ll;
      split2(W1[r*64+c],&hh,&ll);  W1TH[c*64+r]=hh;  W1TL[c*64+r]=ll;
      split2(Ws[r*64+c],&hh,&ll);  WsTH[c*64+r]=hh;  WsTL[c*64+r]=ll;
    }
  } else {
    int kb = (bx-3)*64;
    for (int i=0;i<64;i++){ int k = kb+i;
      split2(Wo[(size_t)k*256 + t],&hh,&ll);
      WoTH[(size_t)t*512 + k]=hh; WoTL[(size_t)t*512 + k]=ll;
    }
  }
}

// ---------------------------------------------------------------------------
// K1 v2: xmid[b,h,n,d] = (x @ Wx + bx)[b,n,h*64+d] + rope.
// ---------------------------------------------------------------------------
__global__ __launch_bounds__(512,1) void k1_gemm_rope(
    const float* __restrict__ x, const float* __restrict__ pos,
    const unsigned short* __restrict__ WxTH, const unsigned short* __restrict__ WxTL,
    const float* __restrict__ bx,
    const float* __restrict__ Wr, const float* __restrict__ br,
    float* __restrict__ xmid)
{
  __shared__ unsigned short SA[2*128*128];  // hi plane, lo plane; [row][128k] swizzled
  __shared__ unsigned short SB[2*64*128];   // hi, lo
  __shared__ float trig[128][8];
  const int tid = threadIdx.x;
  const int wave = tid>>6, lane = tid&63, l15 = lane&15, lq = lane>>4;
  const int m0 = blockIdx.x*128;

  if (tid < 128){
    int m = m0 + tid;
    float a0 = pos[m*3+0];
    float a1 = pos[m*3+1] * 0.046415888336127774f;  // 10000^(-1/3)
    float a2 = pos[m*3+2] * 0.002154434690031884f;  // 10000^(-2/3)
    trig[tid][0]=sinf(a0); trig[tid][1]=sinf(a1); trig[tid][2]=sinf(a2);
    trig[tid][3]=cosf(a0); trig[tid][4]=cosf(a1); trig[tid][5]=cosf(a2);
  }

  short8v aHr[8], aLr[8];
  {
    const int lm = tid>>2, lkq = (tid&3)*32;
    #pragma unroll
    for (int kh=0; kh<2; kh++){
      __syncthreads();
      const float* src = x + (size_t)(m0+lm)*256 + kh*128 + lkq;
      #pragma unroll
      for (int i=0;i<8;i++){
        float4 v = *(const float4*)(src + i*4);
        ushort4 hh, ll;
        split2(v.x,&hh.x,&ll.x); split2(v.y,&hh.y,&ll.y);
        split2(v.z,&hh.z,&ll.z); split2(v.w,&hh.w,&ll.w);
        int G = (lkq>>3) + (i>>1);
        int idx = lm*128 + (((G ^ (lm&15)))<<3) + ((i&1)<<2);
        *(ushort4*)&SA[idx] = hh;
        *(ushort4*)&SA[128*128 + idx] = ll;
      }
      __syncthreads();
      const int row = wave*16 + l15;
      #pragma unroll
      for (int ks=0; ks<4; ks++){
        int idx = row*128 + ((((ks<<2)+lq) ^ l15)<<3);
        aHr[kh*4+ks] = *(const short8v*)&SA[idx];
        aLr[kh*4+ks] = *(const short8v*)&SA[128*128 + idx];
      }
    }
  }

  float ropev[4][4];
  #pragma unroll
  for (int r=0;r<4;r++){
    int tk = wave*16 + lq*4 + r;
    float t0=trig[tk][0],t1=trig[tk][1],t2=trig[tk][2];
    float t3=trig[tk][3],t4=trig[tk][4],t5=trig[tk][5];
    #pragma unroll
    for (int j=0;j<4;j++){
      int d = j*16 + l15;
      float v = br[d];
      v = fmaf(t0, Wr[0*64+d], v);
      v = fmaf(t1, Wr[1*64+d], v);
      v = fmaf(t2, Wr[2*64+d], v);
      v = fmaf(t3, Wr[3*64+d], v);
      v = fmaf(t4, Wr[4*64+d], v);
      v = fmaf(t5, Wr[5*64+d], v);
      ropev[r][j] = v;
    }
  }

  const int bidx = m0 >> 15;
  const int nbase = (m0 & 32767) + wave*16 + lq*4;
  const int ln = tid>>3, lnkq = (tid&7)*16;

  for (int h=0; h<8; h++){
    f32x4 acc[4] = {};
    #pragma unroll
    for (int kh=0; kh<2; kh++){
      __syncthreads();
      {
        const unsigned short* sH = WxTH + (size_t)(h*64+ln)*256 + kh*128 + lnkq;
        const unsigned short* sL = WxTL + (size_t)(h*64+ln)*256 + kh*128 + lnkq;
        int g0 = lnkq>>3;
        int i0 = ln*128 + ((g0     ^ (ln&15))<<3);
        int i1 = ln*128 + (((g0+1) ^ (ln&15))<<3);
        *(uint4*)&SB[i0] = *(const uint4*)sH;
        *(uint4*)&SB[i1] = *(const uint4*)(sH+8);
        *(uint4*)&SB[64*128 + i0] = *(const uint4*)sL;
        *(uint4*)&SB[64*128 + i1] = *(const uint4*)(sL+8);
      }
      __syncthreads();
      #pragma unroll
      for (int ks=0; ks<4; ks++){
        short8v a_h = aHr[kh*4+ks], a_l = aLr[kh*4+ks];
        #pragma unroll
        for (int j=0;j<4;j++){
          int idx = (j*16+l15)*128 + ((((ks<<2)+lq) ^ l15)<<3);
          short8v b_h = *(const short8v*)&SB[idx];
          short8v b_l = *(const short8v*)&SB[64*128 + idx];
          acc[j] = MFMA16(a_h,b_h,acc[j],0,0,0);
          acc[j] = MFMA16(a_h,b_l,acc[j],0,0,0);
          acc[j] = MFMA16(a_l,b_h,acc[j],0,0,0);
        }
      }
    }
    #pragma unroll
    for (int j=0;j<4;j++){
      int col = j*16 + l15;
      float bxv = bx[h*64+col];
      #pragma unroll
      for (int r=0;r<4;r++){
        xmid[(((size_t)(bidx*8+h))*NSEQ + nbase + r)*64 + col] =
          acc[j][r] + bxv + ropev[r][j];
      }
    }
  }
}

// ---------------------------------------------------------------------------
// K2: per (bh, 512-token chunk), 512 threads (8 waves), subtiles of 128 tokens.
// W1T/WsT fragments read from global (L1/L2-resident); gum via float4.
// ---------------------------------------------------------------------------
__global__ __launch_bounds__(512,1) void k2_tile(
  const float* __restrict__ xmid, const float* __restrict__ gum,
  const unsigned short* __restrict__ W1TH, const unsigned short* __restrict__ W1TL,
  const float* __restrict__ b1,
  const float* __restrict__ W2, const float* __restrict__ b2,
  const float* __restrict__ biasp,
  const unsigned short* __restrict__ WsTH, const unsigned short* __restrict__ WsTL,
  const float* __restrict__ bs,
  unsigned* __restrict__ swT, float* __restrict__ part)
{
  __shared__ unsigned short XAh[128*72], XAl[128*72];   // [m][d]
  __shared__ unsigned short XBh[64*136], XBl[64*136];   // [d][m]
  __shared__ unsigned short swh[64*136], swl[64*136];   // [g][m]
  __shared__ float snred[8*64];
  __shared__ float prm[200];

  const int tid = threadIdx.x;
  const int wave = tid>>6, lane = tid&63, l15 = lane&15, lq = lane>>4;
  const int bh = blockIdx.y, chunk = blockIdx.x, h = bh&7;
  const size_t rowbase = (size_t)bh*NSEQ;

  if (tid<64){ prm[tid]=b1[tid]; prm[64+tid]=bs[tid]; prm[128+tid]=W2[tid]; }
  if (tid==64){ prm[192]=b2[0]; prm[193]=biasp[h]; }

  f32x4 acc2[2] = {};
  float snacc[4][4] = {};
  const int gt2 = wave>>1, dbase = (wave&1)*2;

  for (int sub=0; sub<4; ++sub){
    const int n0 = chunk*512 + sub*128;
    __syncthreads();
    { // stage XA [m][d] and XB [d][m] (split)
      const int lm = tid>>2, ldq = (tid&3)*16;
      const float* src = xmid + (rowbase + n0 + lm)*64 + ldq;
      #pragma unroll
      for (int i=0;i<4;i++){
        float4 v = *(const float4*)(src + i*4);
        float vv[4]={v.x,v.y,v.z,v.w};
        ushort4 hh, ll;
        unsigned short* hp=(unsigned short*)&hh; unsigned short* lp=(unsigned short*)&ll;
        #pragma unroll
        for (int j=0;j<4;j++) split2(vv[j], &hp[j], &lp[j]);
        *(ushort4*)&XAh[lm*72 + ldq + i*4] = hh;
        *(ushort4*)&XAl[lm*72 + ldq + i*4] = ll;
        #pragma unroll
        for (int j=0;j<4;j++){
          XBh[(ldq+i*4+j)*136 + lm] = hp[j];
          XBl[(ldq+i*4+j)*136 + lm] = lp[j];
        }
      }
    }
    __syncthreads();

    const int mloc = wave*16 + l15;
    const float* grow = gum + (rowbase + n0 + mloc)*64;
    float4 gu[4];
    #pragma unroll
    for (int gt=0; gt<4; gt++) gu[gt] = *(const float4*)(grow + gt*16 + lq*4);

    // GEMM1': D1[g][m], A=W^T [g][d] (global frags), B=X [m][d]
    f32x4 t1a[4] = {}, lga[4] = {};
    #pragma unroll
    for (int ks=0; ks<2; ks++){
      const int koff = ks*32 + lq*8;
      short8v xH = *(const short8v*)&XAh[(wave*16+l15)*72 + koff];
      short8v xL = *(const short8v*)&XAl[(wave*16+l15)*72 + koff];
      #pragma unroll
      for (int gt=0; gt<4; gt++){
        const int woff = (gt*16+l15)*64 + koff;
        short8v wH = *(const short8v*)(W1TH + woff);
        short8v wL = *(const short8v*)(W1TL + woff);
        t1a[gt] = MFMA16(wH,xH,t1a[gt],0,0,0);
        t1a[gt] = MFMA16(wH,xL,t1a[gt],0,0,0);
        t1a[gt] = MFMA16(wL,xH,t1a[gt],0,0,0);
        short8v sH = *(const short8v*)(WsTH + woff);
        short8v sL = *(const short8v*)(WsTL + woff);
        lga[gt] = MFMA16(sH,xH,lga[gt],0,0,0);
        lga[gt] = MFMA16(sH,xL,lga[gt],0,0,0);
        lga[gt] = MFMA16(sL,xH,lga[gt],0,0,0);
      }
    }

    // temperature (per token = per lane)
    float p = 0.f;
    #pragma unroll
    for (int gt=0; gt<4; gt++)
      #pragma unroll
      for (int r=0;r<4;r++){
        int g = gt*16 + lq*4 + r;
        p += gelu_f(t1a[gt][r] + prm[g]) * prm[128+g];
      }
    p += __shfl_xor(p,16); p += __shfl_xor(p,32);
    float t2 = gelu_f(p + prm[192]);
    float rtemp = 1.f / fmaxf(t2 + prm[193], 0.01f);

    // gumbel softmax over g
    float z[4][4]; float mx = -1e30f;
    #pragma unroll
    for (int gt=0; gt<4; gt++){
      float guv[4] = {gu[gt].x, gu[gt].y, gu[gt].z, gu[gt].w};
      #pragma unroll
      for (int r=0;r<4;r++){
        int g = gt*16 + lq*4 + r;
        float gn = -__logf(-__logf(guv[r]+1e-8f)+1e-8f);
        float zz = (lga[gt][r] + prm[64+g] + gn)*rtemp;
        z[gt][r]=zz; mx = fmaxf(mx, zz);
      }
    }
    mx = fmaxf(mx, __shfl_xor(mx,16)); mx = fmaxf(mx, __shfl_xor(mx,32));
    float se = 0.f;
    #pragma unroll
    for (int gt=0; gt<4; gt++)
      #pragma unroll
      for (int r=0;r<4;r++){ float e = __expf(z[gt][r]-mx); z[gt][r]=e; se += e; }
    se += __shfl_xor(se,16); se += __shfl_xor(se,32);
    float inv = 1.f/se;
    #pragma unroll
    for (int gt=0; gt<4; gt++)
      #pragma unroll
      for (int r=0;r<4;r++){
        float swv = z[gt][r]*inv;
        snacc[gt][r] += swv;
        int g = gt*16 + lq*4 + r;
        unsigned short hh,ll; split2(swv,&hh,&ll);
        swh[g*136 + mloc] = hh; swl[g*136 + mloc] = ll;
      }
    __syncthreads();

    { // write sw to global as packed (hi | lo<<16), layout [bh][g][n]
      const int g = tid>>3, mq = (tid&7)*16;
      #pragma unroll
      for (int i=0;i<4;i++){
        ushort4 hh = *(const ushort4*)&swh[g*136 + mq + i*4];
        ushort4 ll = *(const ushort4*)&swl[g*136 + mq + i*4];
        uint4 pk;
        pk.x = (unsigned)hh.x | ((unsigned)ll.x<<16);
        pk.y = (unsigned)hh.y | ((unsigned)ll.y<<16);
        pk.z = (unsigned)hh.z | ((unsigned)ll.z<<16);
        pk.w = (unsigned)hh.w | ((unsigned)ll.w<<16);
        *(uint4*)(swT + ((size_t)bh*64 + g)*NSEQ + n0 + mq + i*4) = pk;
      }
    }

    // st-GEMM: D2[g][d] += sw^T X, A=sw [g][m], B=X [d][m]
    #pragma unroll
    for (int ks=0; ks<4; ks++){
      const int koff = ks*32 + lq*8;
      short8v aH = *(const short8v*)&swh[(gt2*16+l15)*136 + koff];
      short8v aL = *(const short8v*)&swl[(gt2*16+l15)*136 + koff];
      #pragma unroll
      for (int dt=0; dt<2; dt++){
        const int boff = ((dbase+dt)*16+l15)*136 + koff;
        short8v bH = *(const short8v*)&XBh[boff];
        short8v bL = *(const short8v*)&XBl[boff];
        acc2[dt] = MFMA16(aH,bH,acc2[dt],0,0,0);
        acc2[dt] = MFMA16(aH,bL,acc2[dt],0,0,0);
        acc2[dt] = MFMA16(aL,bH,acc2[dt],0,0,0);
      }
    }
  }

  float* pb = part + ((size_t)bh*64 + chunk)*4160;
  #pragma unroll
  for (int dt=0; dt<2; dt++)
    #pragma unroll
    for (int r=0;r<4;r++){
      int g = gt2*16 + lq*4 + r;
      int d = (dbase+dt)*16 + l15;
      pb[g*64 + d] = acc2[dt][r];
    }
  #pragma unroll
  for (int gt=0; gt<4; gt++)
    #pragma unroll
    for (int r=0;r<4;r++){
      float v = snacc[gt][r];
      v += __shfl_xor(v,1); v += __shfl_xor(v,2);
      v += __shfl_xor(v,4); v += __shfl_xor(v,8);
      if (l15==0) snred[wave*64 + gt*16 + lq*4 + r] = v;
    }
  __syncthreads();
  if (tid < 64){
    float s = 0.f;
    #pragma unroll
    for (int w=0; w<8; w++) s += snred[w*64 + tid];
    pb[4096 + tid] = s;
  }
}

// ---------------------------------------------------------------------------
// K3a: reduce 64 chunk-partials -> stred[bh][4160]. grid (16, 17)
// ---------------------------------------------------------------------------
__global__ __launch_bounds__(256) void k3a_reduce(
    const float* __restrict__ part, float* __restrict__ stred)
{
  const int bh = blockIdx.x;
  const int i = blockIdx.y*256 + threadIdx.x;
  if (i >= 4160) return;
  const float* pb = part + (size_t)bh*64*4160 + i;
  float s[8] = {};
  #pragma unroll 2
  for (int c=0; c<64; c+=8)
    #pragma unroll
    for (int j=0;j<8;j++) s[j] += pb[(size_t)(c+j)*4160];
  stred[bh*4160 + i] = ((s[0]+s[1])+(s[2]+s[3])) + ((s[4]+s[5])+(s[6]+s[7]));
}

// ---------------------------------------------------------------------------
// K3b v2: per (b,h), 4 waves, all matmuls split-bf16 MFMA.
// st->q,k,v -> scores+softmax -> outst -> gate -> gated -> Mt[bh][c][g]
// Weight B-frags read directly from prepped global arrays.
// ---------------------------------------------------------------------------
__global__ __launch_bounds__(256) void k3b_slice(
    const float* __restrict__ stred,
    const unsigned short* __restrict__ WqTH, const unsigned short* __restrict__ WqTL,
    const unsigned short* __restrict__ WkTH, const unsigned short* __restrict__ WkTL,
    const unsigned short* __restrict__ WvTH, const unsigned short* __restrict__ WvTL,
    const unsigned short* __restrict__ Wg1TH, const unsigned short* __restrict__ Wg1TL,
    const unsigned short* __restrict__ Wg2TH, const unsigned short* __restrict__ Wg2TL,
    const unsigned short* __restrict__ WoTH, const unsigned short* __restrict__ WoTL,
    const float* __restrict__ bg1, const float* __restrict__ bg2,
    float* __restrict__ Mt)
{
  __shared__ unsigned short stH[64*72], stL[64*72];
  __shared__ unsigned short qH[64*72],  qL[64*72];
  __shared__ unsigned short kH[64*72],  kL[64*72];
  __shared__ unsigned short vTH[64*72], vTL[64*72];
  __shared__ unsigned short pH[64*72],  pL[64*72];
  __shared__ unsigned short oH[64*72],  oL[64*72];
  __shared__ unsigned short h1H[64*72], h1L[64*72];
  __shared__ unsigned short gH[64*72],  gL[64*72];
  __shared__ float snl[64];

  const int tid = threadIdx.x;
  const int wave = tid>>6, lane = tid&63, l15 = lane&15, lq = lane>>4;
  const int bh = blockIdx.x, h = bh&7;
  const int grow = wave*16 + lq*4;   // D row base for this lane

  if (tid < 64) snl[tid] = stred[bh*4160 + 4096 + tid] + 1e-5f;
  __syncthreads();
  { // st = stred/sn, split -> stH/stL [g][72]
    const int g = tid>>2, doff = (tid&3)*16;
    const float sn = snl[g];
    #pragma unroll
    for (int i=0;i<4;i++){
      float4 v = *(const float4*)(stred + bh*4160 + g*64 + doff + i*4);
      ushort4 hh, ll;
      split2(v.x/sn,&hh.x,&ll.x); split2(v.y/sn,&hh.y,&ll.y);
      split2(v.z/sn,&hh.z,&ll.z); split2(v.w/sn,&hh.w,&ll.w);
      *(ushort4*)&stH[g*72 + doff + i*4] = hh;
      *(ushort4*)&stL[g*72 + doff + i*4] = ll;
    }
  }
  __syncthreads();

  // QKV (rows = wave*16..+15)
  {
    f32x4 aq[4]={}, ak[4]={}, av[4]={};
    #pragma unroll
    for (int ks=0; ks<2; ks++){
      const int koff = ks*32 + lq*8;
      short8v sH = *(const short8v*)&stH[(wave*16+l15)*72 + koff];
      short8v sL = *(const short8v*)&stL[(wave*16+l15)*72 + koff];
      #pragma unroll
      for (int j=0;j<4;j++){
        const int boff = (j*16+l15)*64 + koff;
        short8v bH, bL;
        bH = *(const short8v*)(WqTH+boff); bL = *(const short8v*)(WqTL+boff);
        aq[j]=MFMA16(sH,bH,aq[j],0,0,0); aq[j]=MFMA16(sH,bL,aq[j],0,0,0); aq[j]=MFMA16(sL,bH,aq[j],0,0,0);
        bH = *(const short8v*)(WkTH+boff); bL = *(const short8v*)(WkTL+boff);
        ak[j]=MFMA16(sH,bH,ak[j],0,0,0); ak[j]=MFMA16(sH,bL,ak[j],0,0,0); ak[j]=MFMA16(sL,bH,ak[j],0,0,0);
        bH = *(const short8v*)(WvTH+boff); bL = *(const short8v*)(WvTL+boff);
        av[j]=MFMA16(sH,bH,av[j],0,0,0); av[j]=MFMA16(sH,bL,av[j],0,0,0); av[j]=MFMA16(sL,bH,av[j],0,0,0);
      }
    }
    #pragma unroll
    for (int j=0;j<4;j++){
      #pragma unroll
      for (int r=0;r<4;r++){
        unsigned short hh,ll;
        split2(aq[j][r],&hh,&ll); qH[(grow+r)*72 + j*16+l15]=hh; qL[(grow+r)*72 + j*16+l15]=ll;
        split2(ak[j][r],&hh,&ll); kH[(grow+r)*72 + j*16+l15]=hh; kL[(grow+r)*72 + j*16+l15]=ll;
        split2(av[j][r],&hh,&ll); vTH[(j*16+l15)*72 + grow+r]=hh; vTL[(j*16+l15)*72 + grow+r]=ll;
      }
    }
  }
  __syncthreads();

  // scores + softmax -> P
  {
    f32x4 sc[4]={};
    #pragma unroll
    for (int ks=0; ks<2; ks++){
      const int koff = ks*32 + lq*8;
      short8v aHf = *(const short8v*)&qH[(wave*16+l15)*72 + koff];
      short8v aLf = *(const short8v*)&qL[(wave*16+l15)*72 + koff];
      #pragma unroll
      for (int jt=0; jt<4; jt++){
        const int boff = (jt*16+l15)*72 + koff;
        short8v bH = *(const short8v*)&kH[boff];
        short8v bL = *(const short8v*)&kL[boff];
        sc[jt]=MFMA16(aHf,bH,sc[jt],0,0,0); sc[jt]=MFMA16(aHf,bL,sc[jt],0,0,0); sc[jt]=MFMA16(aLf,bH,sc[jt],0,0,0);
      }
    }
    #pragma unroll
    for (int r=0;r<4;r++){
      float s0=sc[0][r]*0.125f, s1=sc[1][r]*0.125f, s2=sc[2][r]*0.125f, s3=sc[3][r]*0.125f;
      float mx = fmaxf(fmaxf(s0,s1),fmaxf(s2,s3));
      mx=fmaxf(mx,__shfl_xor(mx,1)); mx=fmaxf(mx,__shfl_xor(mx,2));
      mx=fmaxf(mx,__shfl_xor(mx,4)); mx=fmaxf(mx,__shfl_xor(mx,8));
      float e0=__expf(s0-mx), e1=__expf(s1-mx), e2=__expf(s2-mx), e3=__expf(s3-mx);
      float se = e0+e1+e2+e3;
      se+=__shfl_xor(se,1); se+=__shfl_xor(se,2); se+=__shfl_xor(se,4); se+=__shfl_xor(se,8);
      float inv = 1.f/se;
      sc[0][r]=e0*inv; sc[1][r]=e1*inv; sc[2][r]=e2*inv; sc[3][r]=e3*inv;
    }
    #pragma unroll
    for (int jt=0; jt<4; jt++)
      #pragma unroll
      for (int r=0;r<4;r++){
        unsigned short hh,ll; split2(sc[jt][r],&hh,&ll);
        pH[(grow+r)*72 + jt*16+l15]=hh; pL[(grow+r)*72 + jt*16+l15]=ll;
      }
  }
  __syncthreads();

  // outst = P @ v  (keep regs, also write split planes)
  f32x4 os[4] = {};
  {
    #pragma unroll
    for (int ks=0; ks<2; ks++){
      const int koff = ks*32 + lq*8;
      short8v aHf = *(const short8v*)&pH[(wave*16+l15)*72 + koff];
      short8v aLf = *(const short8v*)&pL[(wave*16+l15)*72 + koff];
      #pragma unroll
      for (int dt=0; dt<4; dt++){
        const int boff = (dt*16+l15)*72 + koff;
        short8v bH = *(const short8v*)&vTH[boff];
        short8v bL = *(const short8v*)&vTL[boff];
        os[dt]=MFMA16(aHf,bH,os[dt],0,0,0); os[dt]=MFMA16(aHf,bL,os[dt],0,0,0); os[dt]=MFMA16(aLf,bH,os[dt],0,0,0);
      }
    }
    #pragma unroll
    for (int dt=0; dt<4; dt++)
      #pragma unroll
      for (int r=0;r<4;r++){
        unsigned short hh,ll; split2(os[dt][r],&hh,&ll);
        oH[(grow+r)*72 + dt*16+l15]=hh; oL[(grow+r)*72 + dt*16+l15]=ll;
      }
  }
  __syncthreads();

  // h1 = silu([st, outst] @ Wg1 + bg1)
  {
    f32x4 ha[4] = {};
    #pragma unroll
    for (int ks=0; ks<4; ks++){
      const int koff2 = (ks&1)*32 + lq*8;
      short8v aHf, aLf;
      if (ks<2){ aHf = *(const short8v*)&stH[(wave*16+l15)*72 + koff2];
                 aLf = *(const short8v*)&stL[(wave*16+l15)*72 + koff2]; }
      else     { aHf = *(const short8v*)&oH[(wave*16+l15)*72 + koff2];
                 aLf = *(const short8v*)&oL[(wave*16+l15)*72 + koff2]; }
      #pragma unroll
      for (int dt=0; dt<4; dt++){
        const int boff = (dt*16+l15)*128 + ks*32 + lq*8;
        short8v bH = *(const short8v*)(Wg1TH+boff);
        short8v bL = *(const short8v*)(Wg1TL+boff);
        ha[dt]=MFMA16(aHf,bH,ha[dt],0,0,0); ha[dt]=MFMA16(aHf,bL,ha[dt],0,0,0); ha[dt]=MFMA16(aLf,bH,ha[dt],0,0,0);
      }
    }
    #pragma unroll
    for (int dt=0; dt<4; dt++){
      float bg = bg1[dt*16+l15];
      #pragma unroll
      for (int r=0;r<4;r++){
        float s = ha[dt][r] + bg;
        float sv = s/(1.f+__expf(-s));
        unsigned short hh,ll; split2(sv,&hh,&ll);
        h1H[(grow+r)*72 + dt*16+l15]=hh; h1L[(grow+r)*72 + dt*16+l15]=ll;
      }
    }
  }
  __syncthreads();

  // gated = sigmoid(h1 @ Wg2 + bg2) * outst
  {
    f32x4 ga[4] = {};
    #pragma unroll
    for (int ks=0; ks<2; ks++){
      const int koff = ks*32 + lq*8;
      short8v aHf = *(const short8v*)&h1H[(wave*16+l15)*72 + koff];
      short8v aLf = *(const short8v*)&h1L[(wave*16+l15)*72 + koff];
      #pragma unroll
      for (int dt=0; dt<4; dt++){
        const int boff = (dt*16+l15)*64 + koff;
        short8v bH = *(const short8v*)(Wg2TH+boff);
        short8v bL = *(const short8v*)(Wg2TL+boff);
        ga[dt]=MFMA16(aHf,bH,ga[dt],0,0,0); ga[dt]=MFMA16(aHf,bL,ga[dt],0,0,0); ga[dt]=MFMA16(aLf,bH,ga[dt],0,0,0);
      }
    }
    #pragma unroll
    for (int dt=0; dt<4; dt++){
      float bg = bg2[dt*16+l15];
      #pragma unroll
      for (int r=0;r<4;r++){
        float gate = 1.f/(1.f+__expf(-(ga[dt][r]+bg)));
        float gv = gate * os[dt][r];
        unsigned short hh,ll; split2(gv,&hh,&ll);
        gH[(grow+r)*72 + dt*16+l15]=hh; gL[(grow+r)*72 + dt*16+l15]=ll;
      }
    }
  }
  __syncthreads();

  // M[c][g] = gated @ Wo[h]  (B-frags from WoT [c][512])
  {
    f32x4 mac[16] = {};
    #pragma unroll
    for (int ks=0; ks<2; ks++){
      const int koff = ks*32 + lq*8;
      short8v aHf = *(const short8v*)&gH[(wave*16+l15)*72 + koff];
      short8v aLf = *(const short8v*)&gL[(wave*16+l15)*72 + koff];
      #pragma unroll
      for (int ct=0; ct<16; ct++){
        const size_t boff = (size_t)(ct*16+l15)*512 + h*64 + koff;
        short8v bH = *(const short8v*)(WoTH+boff);
        short8v bL = *(const short8v*)(WoTL+boff);
        mac[ct]=MFMA16(aHf,bH,mac[ct],0,0,0); mac[ct]=MFMA16(aHf,bL,mac[ct],0,0,0); mac[ct]=MFMA16(aLf,bH,mac[ct],0,0,0);
      }
    }
    #pragma unroll
    for (int ct=0; ct<16; ct++)
      #pragma unroll
      for (int r=0;r<4;r++)
        Mt[(size_t)bh*16384 + (size_t)(ct*16+l15)*64 + grow + r] = mac[ct][r];
  }
}

// ---------------------------------------------------------------------------
// K4: out[m][c] = sum_h sw_h(m,g) @ M_h(g,c) + bo. Split-bf16 MFMA.
// ---------------------------------------------------------------------------
__global__ __launch_bounds__(256,2) void k4_out(
  const unsigned* __restrict__ swT, const float* __restrict__ Mt,
  const float* __restrict__ bo, float* __restrict__ out)
{
  __shared__ unsigned short AH[64*72], AL[64*72];     // [m][g]
  __shared__ unsigned short BH[128*72], BL[128*72];   // [c][g]
  const int tid = threadIdx.x;
  const int wave = tid>>6, lane = tid&63, l15 = lane&15, lq = lane>>4;
  const int m0 = blockIdx.x*64, c0 = blockIdx.y*128;
  const int b = m0>>15, nn = m0 & 32767;
  f32x4 acc[8] = {};

  for (int hh=0; hh<8; hh++){
    const int bhh = b*8 + hh;
    __syncthreads();
    {
      const int g = tid>>2, mq = (tid&3)*16;
      const unsigned* src = swT + ((size_t)bhh*64 + g)*NSEQ + nn + mq;
      #pragma unroll
      for (int i=0;i<4;i++){
        uint4 pv = *(const uint4*)(src + i*4);
        unsigned u[4]={pv.x,pv.y,pv.z,pv.w};
        #pragma unroll
        for (int j=0;j<4;j++){
          int m = mq + i*4 + j;
          AH[m*72+g] = (unsigned short)(u[j] & 0xFFFFu);
          AL[m*72+g] = (unsigned short)(u[j] >> 16);
        }
      }
      const int c = tid>>1, gq = (tid&1)*32;
      const float* bsrc = Mt + (size_t)bhh*16384 + (size_t)(c0+c)*64 + gq;
      #pragma unroll
      for (int i=0;i<8;i++){
        float4 v = *(const float4*)(bsrc + i*4);
        float vv[4]={v.x,v.y,v.z,v.w};
        ushort4 hh4, ll4;
        unsigned short* hp=(unsigned short*)&hh4; unsigned short* lp=(unsigned short*)&ll4;
        #pragma unroll
        for (int j=0;j<4;j++) split2(vv[j], &hp[j], &lp[j]);
        *(ushort4*)&BH[c*72 + gq + i*4] = hh4;
        *(ushort4*)&BL[c*72 + gq + i*4] = ll4;
      }
    }
    __syncthreads();
    #pragma unroll
    for (int ks=0; ks<2; ks++){
      const int koff = ks*32 + lq*8;
      short8v aH = *(const short8v*)&AH[(wave*16+l15)*72 + koff];
      short8v aL = *(const short8v*)&AL[(wave*16+l15)*72 + koff];
      #pragma unroll
      for (int ct=0; ct<8; ct++){
        short8v bH = *(const short8v*)&BH[(ct*16+l15)*72 + koff];
        short8v bL = *(const short8v*)&BL[(ct*16+l15)*72 + koff];
        acc[ct] = MFMA16(aH,bH,acc[ct],0,0,0);
        acc[ct] = MFMA16(aH,bL,acc[ct],0,0,0);
        acc[ct] = MFMA16(aL,bH,acc[ct],0,0,0);
      }
    }
  }
  #pragma unroll
  for (int ct=0; ct<8; ct++)
    #pragma unroll
    for (int r=0;r<4;r++){
      int c = c0 + ct*16 + l15;
      out[(size_t)(m0 + wave*16 + lq*4 + r)*256 + c] = acc[ct][r] + bo[c];
    }
}

// ---------------------------------------------------------------------------
extern "C" void kernel_launch(void* const* d_in, const int* in_sizes, int n_in,
                              void* d_out, int out_size, void* d_ws, size_t ws_size,
                              hipStream_t stream) {
  (void)in_sizes; (void)n_in; (void)out_size;
  const float* x    = (const float*)d_in[0];
  const float* pos  = (const float*)d_in[1];
  const float* gum  = (const float*)d_in[2];
  const float* Wx   = (const float*)d_in[3];
  const float* bx   = (const float*)d_in[4];
  const float* W1   = (const float*)d_in[5];
  const float* b1   = (const float*)d_in[6];
  const float* W2   = (const float*)d_in[7];
  const float* b2   = (const float*)d_in[8];
  const float* bias = (const float*)d_in[9];
  const float* Wr   = (const float*)d_in[10];
  const float* br   = (const float*)d_in[11];
  const float* Ws   = (const float*)d_in[12];
  const float* bs   = (const float*)d_in[13];
  const float* Wq   = (const float*)d_in[14];
  const float* Wk   = (const float*)d_in[15];
  const float* Wv   = (const float*)d_in[16];
  const float* Wg1  = (const float*)d_in[17];
  const float* bg1  = (const float*)d_in[18];
  const float* Wg2  = (const float*)d_in[19];
  const float* bg2  = (const float*)d_in[20];
  const float* Wo   = (const float*)d_in[21];
  const float* bo   = (const float*)d_in[22];
  float* out = (float*)d_out;

  float*    xmid  = (float*)d_ws;
  unsigned* swT   = (unsigned*)(xmid + (size_t)33554432);
  float*    partp = (float*)(swT + (size_t)33554432);
  float*    stred = partp + (size_t)4259840;
  unsigned short* WxTH = (unsigned short*)(stred + (size_t)66560);
  unsigned short* WxTL  = WxTH + (size_t)131072;
  unsigned short* WqTH  = WxTL + (size_t)131072;
  unsigned short* WqTL  = WqTH + 4096;
  unsigned short* WkTH  = WqTL + 4096;
  unsigned short* WkTL  = WkTH + 4096;
  unsigned short* WvTH  = WkTL + 4096;
  unsigned short* WvTL  = WvTH + 4096;
  unsigned short* Wg1TH = WvTL + 4096;
  unsigned short* Wg1TL = Wg1TH + 8192;
  unsigned short* Wg2TH = Wg1TL + 8192;
  unsigned short* Wg2TL = Wg2TH + 4096;
  unsigned short* WoTH  = Wg2TL + 4096;
  unsigned short* WoTL  = WoTH + (size_t)131072;
  unsigned short* W1TH  = WoTL + (size_t)131072;
  unsigned short* W1TL  = W1TH + 4096;
  unsigned short* WsTH  = W1TL + 4096;
  unsigned short* WsTL  = WsTH + 4096;
  float*    Mt    = partp;  // alias: part dead after k3a
  const size_t need = ((size_t)33554432*2 + 4259840 + 66560)*4 + (size_t)589824*2;
  if (ws_size < need) return;

  k0_prep<<<512, 256, 0, stream>>>(Wx, WxTH, WxTL);
  k0b_prep<<<11, 256, 0, stream>>>(Wq, Wk, Wv, Wg1, Wg2, Wo, W1, Ws,
      WqTH,WqTL,WkTH,WkTL,WvTH,WvTL,Wg1TH,Wg1TL,Wg2TH,Wg2TL,WoTH,WoTL,W1TH,W1TL,WsTH,WsTL);
  k1_gemm_rope<<<512, 512, 0, stream>>>(x, pos, WxTH, WxTL, bx, Wr, br, xmid);
  k2_tile<<<dim3(64,16), 512, 0, stream>>>(xmid, gum, W1TH, W1TL, b1, W2, b2, bias, WsTH, WsTL, bs, swT, partp);
  k3a_reduce<<<dim3(16,17), 256, 0, stream>>>(partp, stred);
  k3b_slice<<<16, 256, 0, stream>>>(stred, WqTH,WqTL,WkTH,WkTL,WvTH,WvTL,
      Wg1TH,Wg1TL,Wg2TH,Wg2TL,WoTH,WoTL, bg1, bg2, Mt);
  k4_out<<<dim3(1024,2), 256, 0, stream>>>(swT, Mt, bo, out);
}

// Round 8
// 418.046 us; speedup vs baseline: 5.9283x; 1.1473x over previous
//
#include <hip/hip_runtime.h>
#include <math.h>

#define NSEQ 32768

using short8v = __attribute__((ext_vector_type(8))) short;
using f32x4   = __attribute__((ext_vector_type(4))) float;
#define MFMA16 __builtin_amdgcn_mfma_f32_16x16x32_bf16

__device__ __forceinline__ unsigned short f2bf(float f){
  union{float f; unsigned u;} v; v.f = f;
  return (unsigned short)((v.u + 0x7FFFu + ((v.u>>16)&1u))>>16);
}
__device__ __forceinline__ float bf2f(unsigned short h){
  union{unsigned u; float f;} v; v.u = ((unsigned)h)<<16; return v.f;
}
__device__ __forceinline__ void split2(float f, unsigned short* h, unsigned short* l){
  unsigned short hh = f2bf(f);
  *h = hh; *l = f2bf(f - bf2f(hh));
}
__device__ __forceinline__ float gelu_f(float x){
  return 0.5f*x*(1.f + erff(x*0.70710678118654752f));
}

// ---------------------------------------------------------------------------
// K0: Wx [256][512] fp32 -> WxTH/WxTL [512][256] split-bf16 (transposed). Once.
// ---------------------------------------------------------------------------
__global__ __launch_bounds__(256) void k0_prep(const float* __restrict__ Wx,
    unsigned short* __restrict__ WxTH, unsigned short* __restrict__ WxTL)
{
  const int n = blockIdx.x;     // 0..511
  const int k = threadIdx.x;    // 0..255
  float v = Wx[(size_t)k*512 + n];
  unsigned short hh, ll; split2(v,&hh,&ll);
  WxTH[n*256+k]=hh; WxTL[n*256+k]=ll;
}

// ---------------------------------------------------------------------------
// K0b: prep all small weights as transposed split-bf16. grid 11 x 256.
// ---------------------------------------------------------------------------
__global__ __launch_bounds__(256) void k0b_prep(
  const float* __restrict__ Wq, const float* __restrict__ Wk, const float* __restrict__ Wv,
  const float* __restrict__ Wg1, const float* __restrict__ Wg2, const float* __restrict__ Wo,
  const float* __restrict__ W1, const float* __restrict__ Ws,
  unsigned short* __restrict__ WqTH, unsigned short* __restrict__ WqTL,
  unsigned short* __restrict__ WkTH, unsigned short* __restrict__ WkTL,
  unsigned short* __restrict__ WvTH, unsigned short* __restrict__ WvTL,
  unsigned short* __restrict__ Wg1TH, unsigned short* __restrict__ Wg1TL,
  unsigned short* __restrict__ Wg2TH, unsigned short* __restrict__ Wg2TL,
  unsigned short* __restrict__ WoTH, unsigned short* __restrict__ WoTL,
  unsigned short* __restrict__ W1TH, unsigned short* __restrict__ W1TL,
  unsigned short* __restrict__ WsTH, unsigned short* __restrict__ WsTL)
{
  const int bx = blockIdx.x, t = threadIdx.x;
  unsigned short hh, ll;
  if (bx == 0){
    for (int i=0;i<16;i++){ int idx=i*256+t; int r=idx>>6, c=idx&63;
      split2(Wq[r*64+c],&hh,&ll); WqTH[c*64+r]=hh; WqTL[c*64+r]=ll;
      split2(Wk[r*64+c],&hh,&ll); WkTH[c*64+r]=hh; WkTL[c*64+r]=ll;
      split2(Wv[r*64+c],&hh,&ll); WvTH[c*64+r]=hh; WvTL[c*64+r]=ll;
    }
  } else if (bx == 1){
    for (int i=0;i<32;i++){ int idx=i*256+t; int r=idx>>6, c=idx&63;
      split2(Wg1[r*64+c],&hh,&ll); Wg1TH[c*128+r]=hh; Wg1TL[c*128+r]=ll;
    }
  } else if (bx == 2){
    for (int i=0;i<16;i++){ int idx=i*256+t; int r=idx>>6, c=idx&63;
      split2(Wg2[r*64+c],&hh,&ll); Wg2TH[c*64+r]=hh; Wg2TL[c*64+r]=ll;
      split2(W1[r*64+c],&hh,&ll);  W1TH[c*64+r]=hh;  W1TL[c*64+r]=ll;
      split2(Ws[r*64+c],&hh,&ll);  WsTH[c*64+r]=hh;  WsTL[c*64+r]=ll;
    }
  } else {
    int kb = (bx-3)*64;
    for (int i=0;i<64;i++){ int k = kb+i;
      split2(Wo[(size_t)k*256 + t],&hh,&ll);
      WoTH[(size_t)t*512 + k]=hh; WoTL[(size_t)t*512 + k]=ll;
    }
  }
}

// ---------------------------------------------------------------------------
// K1 v2: xmid[b,h,n,d] = (x @ Wx + bx)[b,n,h*64+d] + rope.
// ---------------------------------------------------------------------------
__global__ __launch_bounds__(512,1) void k1_gemm_rope(
    const float* __restrict__ x, const float* __restrict__ pos,
    const unsigned short* __restrict__ WxTH, const unsigned short* __restrict__ WxTL,
    const float* __restrict__ bx,
    const float* __restrict__ Wr, const float* __restrict__ br,
    float* __restrict__ xmid)
{
  __shared__ unsigned short SA[2*128*128];  // hi plane, lo plane; [row][128k] swizzled
  __shared__ unsigned short SB[2*64*128];   // hi, lo
  __shared__ float trig[128][8];
  const int tid = threadIdx.x;
  const int wave = tid>>6, lane = tid&63, l15 = lane&15, lq = lane>>4;
  const int m0 = blockIdx.x*128;

  if (tid < 128){
    int m = m0 + tid;
    float a0 = pos[m*3+0];
    float a1 = pos[m*3+1] * 0.046415888336127774f;  // 10000^(-1/3)
    float a2 = pos[m*3+2] * 0.002154434690031884f;  // 10000^(-2/3)
    trig[tid][0]=sinf(a0); trig[tid][1]=sinf(a1); trig[tid][2]=sinf(a2);
    trig[tid][3]=cosf(a0); trig[tid][4]=cosf(a1); trig[tid][5]=cosf(a2);
  }

  short8v aHr[8], aLr[8];
  {
    const int lm = tid>>2, lkq = (tid&3)*32;
    #pragma unroll
    for (int kh=0; kh<2; kh++){
      __syncthreads();
      const float* src = x + (size_t)(m0+lm)*256 + kh*128 + lkq;
      #pragma unroll
      for (int i=0;i<8;i++){
        float4 v = *(const float4*)(src + i*4);
        ushort4 hh, ll;
        split2(v.x,&hh.x,&ll.x); split2(v.y,&hh.y,&ll.y);
        split2(v.z,&hh.z,&ll.z); split2(v.w,&hh.w,&ll.w);
        int G = (lkq>>3) + (i>>1);
        int idx = lm*128 + (((G ^ (lm&15)))<<3) + ((i&1)<<2);
        *(ushort4*)&SA[idx] = hh;
        *(ushort4*)&SA[128*128 + idx] = ll;
      }
      __syncthreads();
      const int row = wave*16 + l15;
      #pragma unroll
      for (int ks=0; ks<4; ks++){
        int idx = row*128 + ((((ks<<2)+lq) ^ l15)<<3);
        aHr[kh*4+ks] = *(const short8v*)&SA[idx];
        aLr[kh*4+ks] = *(const short8v*)&SA[128*128 + idx];
      }
    }
  }

  float ropev[4][4];
  #pragma unroll
  for (int r=0;r<4;r++){
    int tk = wave*16 + lq*4 + r;
    float t0=trig[tk][0],t1=trig[tk][1],t2=trig[tk][2];
    float t3=trig[tk][3],t4=trig[tk][4],t5=trig[tk][5];
    #pragma unroll
    for (int j=0;j<4;j++){
      int d = j*16 + l15;
      float v = br[d];
      v = fmaf(t0, Wr[0*64+d], v);
      v = fmaf(t1, Wr[1*64+d], v);
      v = fmaf(t2, Wr[2*64+d], v);
      v = fmaf(t3, Wr[3*64+d], v);
      v = fmaf(t4, Wr[4*64+d], v);
      v = fmaf(t5, Wr[5*64+d], v);
      ropev[r][j] = v;
    }
  }

  const int bidx = m0 >> 15;
  const int nbase = (m0 & 32767) + wave*16 + lq*4;
  const int ln = tid>>3, lnkq = (tid&7)*16;

  for (int h=0; h<8; h++){
    f32x4 acc[4] = {};
    #pragma unroll
    for (int kh=0; kh<2; kh++){
      __syncthreads();
      {
        const unsigned short* sH = WxTH + (size_t)(h*64+ln)*256 + kh*128 + lnkq;
        const unsigned short* sL = WxTL + (size_t)(h*64+ln)*256 + kh*128 + lnkq;
        int g0 = lnkq>>3;
        int i0 = ln*128 + ((g0     ^ (ln&15))<<3);
        int i1 = ln*128 + (((g0+1) ^ (ln&15))<<3);
        *(uint4*)&SB[i0] = *(const uint4*)sH;
        *(uint4*)&SB[i1] = *(const uint4*)(sH+8);
        *(uint4*)&SB[64*128 + i0] = *(const uint4*)sL;
        *(uint4*)&SB[64*128 + i1] = *(const uint4*)(sL+8);
      }
      __syncthreads();
      #pragma unroll
      for (int ks=0; ks<4; ks++){
        short8v a_h = aHr[kh*4+ks], a_l = aLr[kh*4+ks];
        #pragma unroll
        for (int j=0;j<4;j++){
          int idx = (j*16+l15)*128 + ((((ks<<2)+lq) ^ l15)<<3);
          short8v b_h = *(const short8v*)&SB[idx];
          short8v b_l = *(const short8v*)&SB[64*128 + idx];
          acc[j] = MFMA16(a_h,b_h,acc[j],0,0,0);
          acc[j] = MFMA16(a_h,b_l,acc[j],0,0,0);
          acc[j] = MFMA16(a_l,b_h,acc[j],0,0,0);
        }
      }
    }
    #pragma unroll
    for (int j=0;j<4;j++){
      int col = j*16 + l15;
      float bxv = bx[h*64+col];
      #pragma unroll
      for (int r=0;r<4;r++){
        xmid[(((size_t)(bidx*8+h))*NSEQ + nbase + r)*64 + col] =
          acc[j][r] + bxv + ropev[r][j];
      }
    }
  }
}

// ---------------------------------------------------------------------------
// K2 v3: W staged in LDS via pure copies from prepped split planes;
// XA/XB staged via register 4x4 transpose (vector LDS writes);
// XB uses 16B-granule XOR swizzle [d][128].
// ---------------------------------------------------------------------------
__global__ __launch_bounds__(512,1) void k2_tile(
  const float* __restrict__ xmid, const float* __restrict__ gum,
  const unsigned short* __restrict__ W1TH, const unsigned short* __restrict__ W1TL,
  const float* __restrict__ b1,
  const float* __restrict__ W2, const float* __restrict__ b2,
  const float* __restrict__ biasp,
  const unsigned short* __restrict__ WsTH, const unsigned short* __restrict__ WsTL,
  const float* __restrict__ bs,
  unsigned* __restrict__ swT, float* __restrict__ part)
{
  __shared__ unsigned short XAh[128*72], XAl[128*72];   // [m][d] pad72
  __shared__ unsigned short XBh[64*128], XBl[64*128];   // [d][m] XOR-swizzled granules
  __shared__ unsigned short W1h[64*72], W1l[64*72];     // [g][d]
  __shared__ unsigned short Wsh[64*72], Wsl[64*72];
  __shared__ unsigned short swh[64*136], swl[64*136];   // [g][m]
  __shared__ float snred[8*64];
  __shared__ float prm[200];

  const int tid = threadIdx.x;
  const int wave = tid>>6, lane = tid&63, l15 = lane&15, lq = lane>>4;
  const int bh = blockIdx.y, chunk = blockIdx.x, h = bh&7;
  const size_t rowbase = (size_t)bh*NSEQ;

  { // stage W: pure 16B copies from prepped global
    const int g = tid>>3, c8 = (tid&7)*8;
    *(uint4*)&W1h[g*72+c8] = *(const uint4*)(W1TH + g*64 + c8);
    *(uint4*)&W1l[g*72+c8] = *(const uint4*)(W1TL + g*64 + c8);
    *(uint4*)&Wsh[g*72+c8] = *(const uint4*)(WsTH + g*64 + c8);
    *(uint4*)&Wsl[g*72+c8] = *(const uint4*)(WsTL + g*64 + c8);
  }
  if (tid<64){ prm[tid]=b1[tid]; prm[64+tid]=bs[tid]; prm[128+tid]=W2[tid]; }
  if (tid==64){ prm[192]=b2[0]; prm[193]=biasp[h]; }

  f32x4 acc2[2] = {};
  float snacc[4][4] = {};
  const int gt2 = wave>>1, dbase = (wave&1)*2;

  for (int sub=0; sub<4; ++sub){
    const int n0 = chunk*512 + sub*128;
    __syncthreads();
    { // stage XA [m][d] + XB [d][m] via register 4x4 transpose
      const int mq = (tid>>4)*4, dq = (tid&15)*4;
      const float* src = xmid + (rowbase + n0 + mq)*64 + dq;
      unsigned short hh[4][4], ll[4][4];
      #pragma unroll
      for (int i=0;i<4;i++){
        float4 v = *(const float4*)(src + i*64);
        split2(v.x,&hh[i][0],&ll[i][0]); split2(v.y,&hh[i][1],&ll[i][1]);
        split2(v.z,&hh[i][2],&ll[i][2]); split2(v.w,&hh[i][3],&ll[i][3]);
        ushort4 th; th.x=hh[i][0]; th.y=hh[i][1]; th.z=hh[i][2]; th.w=hh[i][3];
        ushort4 tl; tl.x=ll[i][0]; tl.y=ll[i][1]; tl.z=ll[i][2]; tl.w=ll[i][3];
        *(ushort4*)&XAh[(mq+i)*72 + dq] = th;
        *(ushort4*)&XAl[(mq+i)*72 + dq] = tl;
      }
      const int gm = mq>>3, mh = mq&7;
      #pragma unroll
      for (int j=0;j<4;j++){
        int d = dq+j;
        int base = d*128 + ((gm ^ (d&15))<<3) + mh;
        ushort4 th; th.x=hh[0][j]; th.y=hh[1][j]; th.z=hh[2][j]; th.w=hh[3][j];
        ushort4 tl; tl.x=ll[0][j]; tl.y=ll[1][j]; tl.z=ll[2][j]; tl.w=ll[3][j];
        *(ushort4*)&XBh[base] = th;
        *(ushort4*)&XBl[base] = tl;
      }
    }
    __syncthreads();

    const int mloc = wave*16 + l15;
    const float* grow = gum + (rowbase + n0 + mloc)*64;
    float4 gu[4];
    #pragma unroll
    for (int gt=0; gt<4; gt++) gu[gt] = *(const float4*)(grow + gt*16 + lq*4);

    // GEMM1': D1[g][m], A=W^T [g][d] (LDS), B=X [m][d] (XA)
    f32x4 t1a[4] = {}, lga[4] = {};
    #pragma unroll
    for (int ks=0; ks<2; ks++){
      const int koff = ks*32 + lq*8;
      short8v xH = *(const short8v*)&XAh[(wave*16+l15)*72 + koff];
      short8v xL = *(const short8v*)&XAl[(wave*16+l15)*72 + koff];
      #pragma unroll
      for (int gt=0; gt<4; gt++){
        const int aoff = (gt*16+l15)*72 + koff;
        short8v wH = *(const short8v*)&W1h[aoff];
        short8v wL = *(const short8v*)&W1l[aoff];
        t1a[gt] = MFMA16(wH,xH,t1a[gt],0,0,0);
        t1a[gt] = MFMA16(wH,xL,t1a[gt],0,0,0);
        t1a[gt] = MFMA16(wL,xH,t1a[gt],0,0,0);
        short8v sH = *(const short8v*)&Wsh[aoff];
        short8v sL = *(const short8v*)&Wsl[aoff];
        lga[gt] = MFMA16(sH,xH,lga[gt],0,0,0);
        lga[gt] = MFMA16(sH,xL,lga[gt],0,0,0);
        lga[gt] = MFMA16(sL,xH,lga[gt],0,0,0);
      }
    }

    // temperature (per token = per lane)
    float p = 0.f;
    #pragma unroll
    for (int gt=0; gt<4; gt++)
      #pragma unroll
      for (int r=0;r<4;r++){
        int g = gt*16 + lq*4 + r;
        p += gelu_f(t1a[gt][r] + prm[g]) * prm[128+g];
      }
    p += __shfl_xor(p,16); p += __shfl_xor(p,32);
    float t2 = gelu_f(p + prm[192]);
    float rtemp = 1.f / fmaxf(t2 + prm[193], 0.01f);

    // gumbel softmax over g
    float z[4][4]; float mx = -1e30f;
    #pragma unroll
    for (int gt=0; gt<4; gt++){
      float guv[4] = {gu[gt].x, gu[gt].y, gu[gt].z, gu[gt].w};
      #pragma unroll
      for (int r=0;r<4;r++){
        int g = gt*16 + lq*4 + r;
        float gn = -__logf(-__logf(guv[r]+1e-8f)+1e-8f);
        float zz = (lga[gt][r] + prm[64+g] + gn)*rtemp;
        z[gt][r]=zz; mx = fmaxf(mx, zz);
      }
    }
    mx = fmaxf(mx, __shfl_xor(mx,16)); mx = fmaxf(mx, __shfl_xor(mx,32));
    float se = 0.f;
    #pragma unroll
    for (int gt=0; gt<4; gt++)
      #pragma unroll
      for (int r=0;r<4;r++){ float e = __expf(z[gt][r]-mx); z[gt][r]=e; se += e; }
    se += __shfl_xor(se,16); se += __shfl_xor(se,32);
    float inv = 1.f/se;
    #pragma unroll
    for (int gt=0; gt<4; gt++)
      #pragma unroll
      for (int r=0;r<4;r++){
        float swv = z[gt][r]*inv;
        snacc[gt][r] += swv;
        int g = gt*16 + lq*4 + r;
        unsigned short hh,ll; split2(swv,&hh,&ll);
        swh[g*136 + mloc] = hh; swl[g*136 + mloc] = ll;
      }
    __syncthreads();

    { // write sw to global as packed (hi | lo<<16), layout [bh][g][n]
      const int g = tid>>3, mq = (tid&7)*16;
      #pragma unroll
      for (int i=0;i<4;i++){
        ushort4 hh = *(const ushort4*)&swh[g*136 + mq + i*4];
        ushort4 ll = *(const ushort4*)&swl[g*136 + mq + i*4];
        uint4 pk;
        pk.x = (unsigned)hh.x | ((unsigned)ll.x<<16);
        pk.y = (unsigned)hh.y | ((unsigned)ll.y<<16);
        pk.z = (unsigned)hh.z | ((unsigned)ll.z<<16);
        pk.w = (unsigned)hh.w | ((unsigned)ll.w<<16);
        *(uint4*)(swT + ((size_t)bh*64 + g)*NSEQ + n0 + mq + i*4) = pk;
      }
    }

    // st-GEMM: D2[g][d] += sw^T X, A=sw [g][m], B=X [d][m] (XB swizzled)
    #pragma unroll
    for (int ks=0; ks<4; ks++){
      const int koff = ks*32 + lq*8;
      short8v aH = *(const short8v*)&swh[(gt2*16+l15)*136 + koff];
      short8v aL = *(const short8v*)&swl[(gt2*16+l15)*136 + koff];
      const int gran = ks*4 + lq;
      #pragma unroll
      for (int dt=0; dt<2; dt++){
        const int d = (dbase+dt)*16 + l15;
        const int boff = d*128 + ((gran ^ (d&15))<<3);
        short8v bH = *(const short8v*)&XBh[boff];
        short8v bL = *(const short8v*)&XBl[boff];
        acc2[dt] = MFMA16(aH,bH,acc2[dt],0,0,0);
        acc2[dt] = MFMA16(aH,bL,acc2[dt],0,0,0);
        acc2[dt] = MFMA16(aL,bH,acc2[dt],0,0,0);
      }
    }
  }

  float* pb = part + ((size_t)bh*64 + chunk)*4160;
  #pragma unroll
  for (int dt=0; dt<2; dt++)
    #pragma unroll
    for (int r=0;r<4;r++){
      int g = gt2*16 + lq*4 + r;
      int d = (dbase+dt)*16 + l15;
      pb[g*64 + d] = acc2[dt][r];
    }
  #pragma unroll
  for (int gt=0; gt<4; gt++)
    #pragma unroll
    for (int r=0;r<4;r++){
      float v = snacc[gt][r];
      v += __shfl_xor(v,1); v += __shfl_xor(v,2);
      v += __shfl_xor(v,4); v += __shfl_xor(v,8);
      if (l15==0) snred[wave*64 + gt*16 + lq*4 + r] = v;
    }
  __syncthreads();
  if (tid < 64){
    float s = 0.f;
    #pragma unroll
    for (int w=0; w<8; w++) s += snred[w*64 + tid];
    pb[4096 + tid] = s;
  }
}

// ---------------------------------------------------------------------------
// K3a: reduce 64 chunk-partials -> stred[bh][4160]. grid (16, 17)
// ---------------------------------------------------------------------------
__global__ __launch_bounds__(256) void k3a_reduce(
    const float* __restrict__ part, float* __restrict__ stred)
{
  const int bh = blockIdx.x;
  const int i = blockIdx.y*256 + threadIdx.x;
  if (i >= 4160) return;
  const float* pb = part + (size_t)bh*64*4160 + i;
  float s[8] = {};
  #pragma unroll 2
  for (int c=0; c<64; c+=8)
    #pragma unroll
    for (int j=0;j<8;j++) s[j] += pb[(size_t)(c+j)*4160];
  stred[bh*4160 + i] = ((s[0]+s[1])+(s[2]+s[3])) + ((s[4]+s[5])+(s[6]+s[7]));
}

// ---------------------------------------------------------------------------
// K3b v2: per (b,h), 4 waves, all matmuls split-bf16 MFMA. Mt written PACKED.
// ---------------------------------------------------------------------------
__global__ __launch_bounds__(256) void k3b_slice(
    const float* __restrict__ stred,
    const unsigned short* __restrict__ WqTH, const unsigned short* __restrict__ WqTL,
    const unsigned short* __restrict__ WkTH, const unsigned short* __restrict__ WkTL,
    const unsigned short* __restrict__ WvTH, const unsigned short* __restrict__ WvTL,
    const unsigned short* __restrict__ Wg1TH, const unsigned short* __restrict__ Wg1TL,
    const unsigned short* __restrict__ Wg2TH, const unsigned short* __restrict__ Wg2TL,
    const unsigned short* __restrict__ WoTH, const unsigned short* __restrict__ WoTL,
    const float* __restrict__ bg1, const float* __restrict__ bg2,
    unsigned* __restrict__ MtP)
{
  __shared__ unsigned short stH[64*72], stL[64*72];
  __shared__ unsigned short qH[64*72],  qL[64*72];
  __shared__ unsigned short kH[64*72],  kL[64*72];
  __shared__ unsigned short vTH[64*72], vTL[64*72];
  __shared__ unsigned short pH[64*72],  pL[64*72];
  __shared__ unsigned short oH[64*72],  oL[64*72];
  __shared__ unsigned short h1H[64*72], h1L[64*72];
  __shared__ unsigned short gH[64*72],  gL[64*72];
  __shared__ float snl[64];

  const int tid = threadIdx.x;
  const int wave = tid>>6, lane = tid&63, l15 = lane&15, lq = lane>>4;
  const int bh = blockIdx.x, h = bh&7;
  const int grow = wave*16 + lq*4;

  if (tid < 64) snl[tid] = stred[bh*4160 + 4096 + tid] + 1e-5f;
  __syncthreads();
  {
    const int g = tid>>2, doff = (tid&3)*16;
    const float sn = snl[g];
    #pragma unroll
    for (int i=0;i<4;i++){
      float4 v = *(const float4*)(stred + bh*4160 + g*64 + doff + i*4);
      ushort4 hh, ll;
      split2(v.x/sn,&hh.x,&ll.x); split2(v.y/sn,&hh.y,&ll.y);
      split2(v.z/sn,&hh.z,&ll.z); split2(v.w/sn,&hh.w,&ll.w);
      *(ushort4*)&stH[g*72 + doff + i*4] = hh;
      *(ushort4*)&stL[g*72 + doff + i*4] = ll;
    }
  }
  __syncthreads();

  // QKV
  {
    f32x4 aq[4]={}, ak[4]={}, av[4]={};
    #pragma unroll
    for (int ks=0; ks<2; ks++){
      const int koff = ks*32 + lq*8;
      short8v sH = *(const short8v*)&stH[(wave*16+l15)*72 + koff];
      short8v sL = *(const short8v*)&stL[(wave*16+l15)*72 + koff];
      #pragma unroll
      for (int j=0;j<4;j++){
        const int boff = (j*16+l15)*64 + koff;
        short8v bH, bL;
        bH = *(const short8v*)(WqTH+boff); bL = *(const short8v*)(WqTL+boff);
        aq[j]=MFMA16(sH,bH,aq[j],0,0,0); aq[j]=MFMA16(sH,bL,aq[j],0,0,0); aq[j]=MFMA16(sL,bH,aq[j],0,0,0);
        bH = *(const short8v*)(WkTH+boff); bL = *(const short8v*)(WkTL+boff);
        ak[j]=MFMA16(sH,bH,ak[j],0,0,0); ak[j]=MFMA16(sH,bL,ak[j],0,0,0); ak[j]=MFMA16(sL,bH,ak[j],0,0,0);
        bH = *(const short8v*)(WvTH+boff); bL = *(const short8v*)(WvTL+boff);
        av[j]=MFMA16(sH,bH,av[j],0,0,0); av[j]=MFMA16(sH,bL,av[j],0,0,0); av[j]=MFMA16(sL,bH,av[j],0,0,0);
      }
    }
    #pragma unroll
    for (int j=0;j<4;j++){
      #pragma unroll
      for (int r=0;r<4;r++){
        unsigned short hh,ll;
        split2(aq[j][r],&hh,&ll); qH[(grow+r)*72 + j*16+l15]=hh; qL[(grow+r)*72 + j*16+l15]=ll;
        split2(ak[j][r],&hh,&ll); kH[(grow+r)*72 + j*16+l15]=hh; kL[(grow+r)*72 + j*16+l15]=ll;
        split2(av[j][r],&hh,&ll); vTH[(j*16+l15)*72 + grow+r]=hh; vTL[(j*16+l15)*72 + grow+r]=ll;
      }
    }
  }
  __syncthreads();

  // scores + softmax -> P
  {
    f32x4 sc[4]={};
    #pragma unroll
    for (int ks=0; ks<2; ks++){
      const int koff = ks*32 + lq*8;
      short8v aHf = *(const short8v*)&qH[(wave*16+l15)*72 + koff];
      short8v aLf = *(const short8v*)&qL[(wave*16+l15)*72 + koff];
      #pragma unroll
      for (int jt=0; jt<4; jt++){
        const int boff = (jt*16+l15)*72 + koff;
        short8v bH = *(const short8v*)&kH[boff];
        short8v bL = *(const short8v*)&kL[boff];
        sc[jt]=MFMA16(aHf,bH,sc[jt],0,0,0); sc[jt]=MFMA16(aHf,bL,sc[jt],0,0,0); sc[jt]=MFMA16(aLf,bH,sc[jt],0,0,0);
      }
    }
    #pragma unroll
    for (int r=0;r<4;r++){
      float s0=sc[0][r]*0.125f, s1=sc[1][r]*0.125f, s2=sc[2][r]*0.125f, s3=sc[3][r]*0.125f;
      float mx = fmaxf(fmaxf(s0,s1),fmaxf(s2,s3));
      mx=fmaxf(mx,__shfl_xor(mx,1)); mx=fmaxf(mx,__shfl_xor(mx,2));
      mx=fmaxf(mx,__shfl_xor(mx,4)); mx=fmaxf(mx,__shfl_xor(mx,8));
      float e0=__expf(s0-mx), e1=__expf(s1-mx), e2=__expf(s2-mx), e3=__expf(s3-mx);
      float se = e0+e1+e2+e3;
      se+=__shfl_xor(se,1); se+=__shfl_xor(se,2); se+=__shfl_xor(se,4); se+=__shfl_xor(se,8);
      float inv = 1.f/se;
      sc[0][r]=e0*inv; sc[1][r]=e1*inv; sc[2][r]=e2*inv; sc[3][r]=e3*inv;
    }
    #pragma unroll
    for (int jt=0; jt<4; jt++)
      #pragma unroll
      for (int r=0;r<4;r++){
        unsigned short hh,ll; split2(sc[jt][r],&hh,&ll);
        pH[(grow+r)*72 + jt*16+l15]=hh; pL[(grow+r)*72 + jt*16+l15]=ll;
      }
  }
  __syncthreads();

  // outst = P @ v
  f32x4 os[4] = {};
  {
    #pragma unroll
    for (int ks=0; ks<2; ks++){
      const int koff = ks*32 + lq*8;
      short8v aHf = *(const short8v*)&pH[(wave*16+l15)*72 + koff];
      short8v aLf = *(const short8v*)&pL[(wave*16+l15)*72 + koff];
      #pragma unroll
      for (int dt=0; dt<4; dt++){
        const int boff = (dt*16+l15)*72 + koff;
        short8v bH = *(const short8v*)&vTH[boff];
        short8v bL = *(const short8v*)&vTL[boff];
        os[dt]=MFMA16(aHf,bH,os[dt],0,0,0); os[dt]=MFMA16(aHf,bL,os[dt],0,0,0); os[dt]=MFMA16(aLf,bH,os[dt],0,0,0);
      }
    }
    #pragma unroll
    for (int dt=0; dt<4; dt++)
      #pragma unroll
      for (int r=0;r<4;r++){
        unsigned short hh,ll; split2(os[dt][r],&hh,&ll);
        oH[(grow+r)*72 + dt*16+l15]=hh; oL[(grow+r)*72 + dt*16+l15]=ll;
      }
  }
  __syncthreads();

  // h1 = silu([st, outst] @ Wg1 + bg1)
  {
    f32x4 ha[4] = {};
    #pragma unroll
    for (int ks=0; ks<4; ks++){
      const int koff2 = (ks&1)*32 + lq*8;
      short8v aHf, aLf;
      if (ks<2){ aHf = *(const short8v*)&stH[(wave*16+l15)*72 + koff2];
                 aLf = *(const short8v*)&stL[(wave*16+l15)*72 + koff2]; }
      else     { aHf = *(const short8v*)&oH[(wave*16+l15)*72 + koff2];
                 aLf = *(const short8v*)&oL[(wave*16+l15)*72 + koff2]; }
      #pragma unroll
      for (int dt=0; dt<4; dt++){
        const int boff = (dt*16+l15)*128 + ks*32 + lq*8;
        short8v bH = *(const short8v*)(Wg1TH+boff);
        short8v bL = *(const short8v*)(Wg1TL+boff);
        ha[dt]=MFMA16(aHf,bH,ha[dt],0,0,0); ha[dt]=MFMA16(aHf,bL,ha[dt],0,0,0); ha[dt]=MFMA16(aLf,bH,ha[dt],0,0,0);
      }
    }
    #pragma unroll
    for (int dt=0; dt<4; dt++){
      float bg = bg1[dt*16+l15];
      #pragma unroll
      for (int r=0;r<4;r++){
        float s = ha[dt][r] + bg;
        float sv = s/(1.f+__expf(-s));
        unsigned short hh,ll; split2(sv,&hh,&ll);
        h1H[(grow+r)*72 + dt*16+l15]=hh; h1L[(grow+r)*72 + dt*16+l15]=ll;
      }
    }
  }
  __syncthreads();

  // gated = sigmoid(h1 @ Wg2 + bg2) * outst
  {
    f32x4 ga[4] = {};
    #pragma unroll
    for (int ks=0; ks<2; ks++){
      const int koff = ks*32 + lq*8;
      short8v aHf = *(const short8v*)&h1H[(wave*16+l15)*72 + koff];
      short8v aLf = *(const short8v*)&h1L[(wave*16+l15)*72 + koff];
      #pragma unroll
      for (int dt=0; dt<4; dt++){
        const int boff = (dt*16+l15)*64 + koff;
        short8v bH = *(const short8v*)(Wg2TH+boff);
        short8v bL = *(const short8v*)(Wg2TL+boff);
        ga[dt]=MFMA16(aHf,bH,ga[dt],0,0,0); ga[dt]=MFMA16(aHf,bL,ga[dt],0,0,0); ga[dt]=MFMA16(aLf,bH,ga[dt],0,0,0);
      }
    }
    #pragma unroll
    for (int dt=0; dt<4; dt++){
      float bg = bg2[dt*16+l15];
      #pragma unroll
      for (int r=0;r<4;r++){
        float gate = 1.f/(1.f+__expf(-(ga[dt][r]+bg)));
        float gv = gate * os[dt][r];
        unsigned short hh,ll; split2(gv,&hh,&ll);
        gH[(grow+r)*72 + dt*16+l15]=hh; gL[(grow+r)*72 + dt*16+l15]=ll;
      }
    }
  }
  __syncthreads();

  // M[c][g] = gated @ Wo[h]  -> packed (hi | lo<<16)
  {
    f32x4 mac[16] = {};
    #pragma unroll
    for (int ks=0; ks<2; ks++){
      const int koff = ks*32 + lq*8;
      short8v aHf = *(const short8v*)&gH[(wave*16+l15)*72 + koff];
      short8v aLf = *(const short8v*)&gL[(wave*16+l15)*72 + koff];
      #pragma unroll
      for (int ct=0; ct<16; ct++){
        const size_t boff = (size_t)(ct*16+l15)*512 + h*64 + koff;
        short8v bH = *(const short8v*)(WoTH+boff);
        short8v bL = *(const short8v*)(WoTL+boff);
        mac[ct]=MFMA16(aHf,bH,mac[ct],0,0,0); mac[ct]=MFMA16(aHf,bL,mac[ct],0,0,0); mac[ct]=MFMA16(aLf,bH,mac[ct],0,0,0);
      }
    }
    #pragma unroll
    for (int ct=0; ct<16; ct++)
      #pragma unroll
      for (int r=0;r<4;r++){
        unsigned short hh,ll; split2(mac[ct][r],&hh,&ll);
        MtP[(size_t)bh*16384 + (size_t)(ct*16+l15)*64 + grow + r] =
          (unsigned)hh | ((unsigned)ll<<16);
      }
  }
}

// ---------------------------------------------------------------------------
// K4: out[m][c] = sum_h sw_h(m,g) @ M_h(g,c) + bo. Split-bf16 MFMA.
// B-stage consumes packed Mt (bit unpack, vector LDS writes, no split2).
// ---------------------------------------------------------------------------
__global__ __launch_bounds__(256,2) void k4_out(
  const unsigned* __restrict__ swT, const unsigned* __restrict__ MtP,
  const float* __restrict__ bo, float* __restrict__ out)
{
  __shared__ unsigned short AH[64*72], AL[64*72];     // [m][g]
  __shared__ unsigned short BH[128*72], BL[128*72];   // [c][g]
  const int tid = threadIdx.x;
  const int wave = tid>>6, lane = tid&63, l15 = lane&15, lq = lane>>4;
  const int m0 = blockIdx.x*64, c0 = blockIdx.y*128;
  const int b = m0>>15, nn = m0 & 32767;
  f32x4 acc[8] = {};

  for (int hh=0; hh<8; hh++){
    const int bhh = b*8 + hh;
    __syncthreads();
    {
      const int g = tid>>2, mq = (tid&3)*16;
      const unsigned* src = swT + ((size_t)bhh*64 + g)*NSEQ + nn + mq;
      #pragma unroll
      for (int i=0;i<4;i++){
        uint4 pv = *(const uint4*)(src + i*4);
        unsigned u[4]={pv.x,pv.y,pv.z,pv.w};
        #pragma unroll
        for (int j=0;j<4;j++){
          int m = mq + i*4 + j;
          AH[m*72+g] = (unsigned short)(u[j] & 0xFFFFu);
          AL[m*72+g] = (unsigned short)(u[j] >> 16);
        }
      }
      const int c = tid>>1, gq = (tid&1)*32;
      const unsigned* bsrc = MtP + (size_t)bhh*16384 + (size_t)(c0+c)*64 + gq;
      #pragma unroll
      for (int i=0;i<8;i++){
        uint4 pv = *(const uint4*)(bsrc + i*4);
        ushort4 hh4, ll4;
        hh4.x=(unsigned short)(pv.x&0xFFFFu); ll4.x=(unsigned short)(pv.x>>16);
        hh4.y=(unsigned short)(pv.y&0xFFFFu); ll4.y=(unsigned short)(pv.y>>16);
        hh4.z=(unsigned short)(pv.z&0xFFFFu); ll4.z=(unsigned short)(pv.z>>16);
        hh4.w=(unsigned short)(pv.w&0xFFFFu); ll4.w=(unsigned short)(pv.w>>16);
        *(ushort4*)&BH[c*72 + gq + i*4] = hh4;
        *(ushort4*)&BL[c*72 + gq + i*4] = ll4;
      }
    }
    __syncthreads();
    #pragma unroll
    for (int ks=0; ks<2; ks++){
      const int koff = ks*32 + lq*8;
      short8v aH = *(const short8v*)&AH[(wave*16+l15)*72 + koff];
      short8v aL = *(const short8v*)&AL[(wave*16+l15)*72 + koff];
      #pragma unroll
      for (int ct=0; ct<8; ct++){
        short8v bH = *(const short8v*)&BH[(ct*16+l15)*72 + koff];
        short8v bL = *(const short8v*)&BL[(ct*16+l15)*72 + koff];
        acc[ct] = MFMA16(aH,bH,acc[ct],0,0,0);
        acc[ct] = MFMA16(aH,bL,acc[ct],0,0,0);
        acc[ct] = MFMA16(aL,bH,acc[ct],0,0,0);
      }
    }
  }
  #pragma unroll
  for (int ct=0; ct<8; ct++)
    #pragma unroll
    for (int r=0;r<4;r++){
      int c = c0 + ct*16 + l15;
      out[(size_t)(m0 + wave*16 + lq*4 + r)*256 + c] = acc[ct][r] + bo[c];
    }
}

// ---------------------------------------------------------------------------
extern "C" void kernel_launch(void* const* d_in, const int* in_sizes, int n_in,
                              void* d_out, int out_size, void* d_ws, size_t ws_size,
                              hipStream_t stream) {
  (void)in_sizes; (void)n_in; (void)out_size;
  const float* x    = (const float*)d_in[0];
  const float* pos  = (const float*)d_in[1];
  const float* gum  = (const float*)d_in[2];
  const float* Wx   = (const float*)d_in[3];
  const float* bx   = (const float*)d_in[4];
  const float* W1   = (const float*)d_in[5];
  const float* b1   = (const float*)d_in[6];
  const float* W2   = (const float*)d_in[7];
  const float* b2   = (const float*)d_in[8];
  const float* bias = (const float*)d_in[9];
  const float* Wr   = (const float*)d_in[10];
  const float* br   = (const float*)d_in[11];
  const float* Ws   = (const float*)d_in[12];
  const float* bs   = (const float*)d_in[13];
  const float* Wq   = (const float*)d_in[14];
  const float* Wk   = (const float*)d_in[15];
  const float* Wv   = (const float*)d_in[16];
  const float* Wg1  = (const float*)d_in[17];
  const float* bg1  = (const float*)d_in[18];
  const float* Wg2  = (const float*)d_in[19];
  const float* bg2  = (const float*)d_in[20];
  const float* Wo   = (const float*)d_in[21];
  const float* bo   = (const float*)d_in[22];
  float* out = (float*)d_out;

  float*    xmid  = (float*)d_ws;
  unsigned* swT   = (unsigned*)(xmid + (size_t)33554432);
  float*    partp = (float*)(swT + (size_t)33554432);
  float*    stred = partp + (size_t)4259840;
  unsigned short* WxTH = (unsigned short*)(stred + (size_t)66560);
  unsigned short* WxTL  = WxTH + (size_t)131072;
  unsigned short* WqTH  = WxTL + (size_t)131072;
  unsigned short* WqTL  = WqTH + 4096;
  unsigned short* WkTH  = WqTL + 4096;
  unsigned short* WkTL  = WkTH + 4096;
  unsigned short* WvTH  = WkTL + 4096;
  unsigned short* WvTL  = WvTH + 4096;
  unsigned short* Wg1TH = WvTL + 4096;
  unsigned short* Wg1TL = Wg1TH + 8192;
  unsigned short* Wg2TH = Wg1TL + 8192;
  unsigned short* Wg2TL = Wg2TH + 4096;
  unsigned short* WoTH  = Wg2TL + 4096;
  unsigned short* WoTL  = WoTH + (size_t)131072;
  unsigned short* W1TH  = WoTL + (size_t)131072;
  unsigned short* W1TL  = W1TH + 4096;
  unsigned short* WsTH  = W1TL + 4096;
  unsigned short* WsTL  = WsTH + 4096;
  unsigned* MtP = (unsigned*)partp;  // alias: part dead after k3a
  const size_t need = ((size_t)33554432*2 + 4259840 + 66560)*4 + (size_t)589824*2;
  if (ws_size < need) return;

  k0_prep<<<512, 256, 0, stream>>>(Wx, WxTH, WxTL);
  k0b_prep<<<11, 256, 0, stream>>>(Wq, Wk, Wv, Wg1, Wg2, Wo, W1, Ws,
      WqTH,WqTL,WkTH,WkTL,WvTH,WvTL,Wg1TH,Wg1TL,Wg2TH,Wg2TL,WoTH,WoTL,W1TH,W1TL,WsTH,WsTL);
  k1_gemm_rope<<<512, 512, 0, stream>>>(x, pos, WxTH, WxTL, bx, Wr, br, xmid);
  k2_tile<<<dim3(64,16), 512, 0, stream>>>(xmid, gum, W1TH, W1TL, b1, W2, b2, bias, WsTH, WsTL, bs, swT, partp);
  k3a_reduce<<<dim3(16,17), 256, 0, stream>>>(partp, stred);
  k3b_slice<<<16, 256, 0, stream>>>(stred, WqTH,WqTL,WkTH,WkTL,WvTH,WvTL,
      Wg1TH,Wg1TL,Wg2TH,Wg2TL,WoTH,WoTL, bg1, bg2, MtP);
  k4_out<<<dim3(1024,2), 256, 0, stream>>>(swT, MtP, bo, out);
}